// Round 5
// baseline (253.805 us; speedup 1.0000x reference)
//
#include <hip/hip_runtime.h>
#include <stdint.h>

// ---------------- problem constants (hard-coded from reference) ----------------
#define B_    2
#define N_    1000
#define C_    256
#define H_    50
#define W_    50
#define P_    7
#define NCLS  91
#define REP_  1024
#define DIN   (C_ * P_ * P_)   // 12544
#define M_    (B_ * N_)        // 2000
#define MPAD  2048
#define HOUT  512              // padded head cols (91 cls + 364 bbox = 455 real)
#define DET_  100
#define NMSM  (N_ * 90)        // 90000 candidates per batch
#define NEGV  (-1000000000.0f)
#define SCALE_ 0.0625f
#define IMGF  800.0f
#define BBOX_CLIPF 4.135166556742356f  // log(1000/16)

#define ROISEG 7               // blocks per roi row; 12544/7 = 1792 = 7*256
#define SEGLEN 1792

typedef __bf16 bf16_t;
typedef __attribute__((ext_vector_type(8))) __bf16 bf16x8;
typedef __attribute__((ext_vector_type(4))) __bf16 bf16x4;
typedef __attribute__((ext_vector_type(4))) float f32x4;
typedef __attribute__((ext_vector_type(4))) int i32x4;

// async global->LDS, 16B per lane. LDS dest must be wave-uniform base (+lane*16 by HW).
__device__ __forceinline__ void gload16(const void* g, void* l) {
  auto gp = (const __attribute__((address_space(1))) uint32_t*)(uintptr_t)g;
  auto lp = (__attribute__((address_space(3))) uint32_t*)(uint32_t)(uintptr_t)l;
  __builtin_amdgcn_global_load_lds(gp, lp, 16, 0, 0);
}

// ---------------- ROI align -> A bf16 [MPAD][DIN] (rows >= 2000 zeroed) ----------------
__global__ __launch_bounds__(256) void roi_kernel(const float* __restrict__ features,
                                                  const float* __restrict__ proposals,
                                                  bf16_t* __restrict__ A) {
  const int blk = blockIdx.x;
  const int n = blk / ROISEG;
  const int seg = blk - n * ROISEG;
  const int t = threadIdx.x;
  bf16_t* aseg = A + (size_t)n * DIN + seg * SEGLEN;
  if (n >= M_) {
    if (t < SEGLEN / 8) ((f32x4*)aseg)[t] = f32x4{0.f, 0.f, 0.f, 0.f};
    return;
  }
  __shared__ __align__(16) int   s_o[49][4];  // o00,o01,o10,o11 (feature-plane offsets)
  __shared__ __align__(16) float s_w[49][4];  // w00,w01,w10,w11
  __shared__ __align__(16) bf16_t s_out[SEGLEN];
  if (t < 49) {
    const float* p = proposals + n * 4;
    const int py = t / 7, px = t - (t / 7) * 7;
    float y1 = p[1] * SCALE_, y2 = p[3] * SCALE_;
    float bh = (y2 - y1) * (1.0f / 7.0f);
    float y = y1 + ((float)py + 0.5f) * bh - 0.5f;
    y = fminf(fmaxf(y, 0.0f), 49.0f);
    int y0 = (int)floorf(y);
    int y1i = min(y0 + 1, 49);
    float ly = y - (float)y0, hy = 1.0f - ly;
    float x1 = p[0] * SCALE_, x2 = p[2] * SCALE_;
    float bw = (x2 - x1) * (1.0f / 7.0f);
    float x = x1 + ((float)px + 0.5f) * bw - 0.5f;
    x = fminf(fmaxf(x, 0.0f), 49.0f);
    int x0 = (int)floorf(x);
    int x1i = min(x0 + 1, 49);
    float lx = x - (float)x0, hx = 1.0f - lx;
    s_o[t][0] = y0 * W_ + x0;
    s_o[t][1] = y0 * W_ + x1i;
    s_o[t][2] = y1i * W_ + x0;
    s_o[t][3] = y1i * W_ + x1i;
    s_w[t][0] = hy * hx;
    s_w[t][1] = hy * lx;
    s_w[t][2] = ly * hx;
    s_w[t][3] = ly * lx;
  }
  __syncthreads();
  const int b = (n >= N_) ? 1 : 0;
  const float* fb = features + (size_t)b * (C_ * H_ * W_);
  int e0 = seg * SEGLEN + t;
  int c = e0 / 49;
  int pp = e0 - c * 49;
#pragma unroll
  for (int j = 0; j < ROISEG; ++j) {
    const i32x4 ov = *(const i32x4*)&s_o[pp][0];
    const f32x4 wv = *(const f32x4*)&s_w[pp][0];
    const float* fc = fb + c * (H_ * W_);
    float v = fc[ov[0]] * wv[0] + fc[ov[1]] * wv[1] + fc[ov[2]] * wv[2] + fc[ov[3]] * wv[3];
    s_out[j * 256 + t] = (bf16_t)v;
    pp += 11;
    c += 5;
    if (pp >= 49) { pp -= 49; c += 1; }
  }
  __syncthreads();
  if (t < SEGLEN / 8) ((f32x4*)aseg)[t] = ((const f32x4*)s_out)[t];
}

// ---------------- transpose+convert: in f32 [K][N] -> out bf16 [N][K] ----------------
__global__ __launch_bounds__(256) void transpose_kernel(const float* __restrict__ in,
                                                        bf16_t* __restrict__ out,
                                                        int K, int N) {
  __shared__ float tile[32][33];
  const int k0 = blockIdx.x * 32;
  const int n0 = blockIdx.y * 32;
  const int tx = threadIdx.x & 31;
  const int ty = threadIdx.x >> 5;  // 0..7
#pragma unroll
  for (int j = 0; j < 4; ++j) {
    int ky = ty + j * 8;
    tile[ky][tx] = in[(size_t)(k0 + ky) * N + n0 + tx];
  }
  __syncthreads();
  const int qx = threadIdx.x & 7;   // k quad
  const int ny = threadIdx.x >> 3;  // 0..31
  bf16x4 o;
#pragma unroll
  for (int i = 0; i < 4; ++i) o[i] = (bf16_t)tile[4 * qx + i][ny];
  *(bf16x4*)(&out[(size_t)(n0 + ny) * K + k0 + 4 * qx]) = o;
}

// ---------------- build concat head weight (B^T) and bias ----------------
__global__ __launch_bounds__(256) void headw_kernel(const float* __restrict__ wcls,
                                                    const float* __restrict__ wbb,
                                                    bf16_t* __restrict__ wht) {
  int idx = blockIdx.x * 256 + threadIdx.x;  // HOUT*REP_ total
  int j = idx >> 10;        // output column (row of B^T), 0..511
  int k = idx & 1023;
  float v = 0.0f;
  if (j < NCLS) v = wcls[(size_t)k * NCLS + j];
  else if (j < 455) v = wbb[(size_t)k * 364 + (j - NCLS)];
  wht[idx] = (bf16_t)v;
}

__global__ void headb_kernel(const float* __restrict__ bcls,
                             const float* __restrict__ bbb,
                             float* __restrict__ biash) {
  int j = threadIdx.x;  // 512
  float v = 0.0f;
  if (j < NCLS) v = bcls[j];
  else if (j < 455) v = bbb[j - NCLS];
  biash[j] = v;
}

// ---------------- bf16 MFMA GEMM, split-K, XCD-pinned K-chunks ----------------
// Flat 1-D grid, chunk = wgid % KC -> with round-robin dispatch, each K-chunk's
// blocks land on a fixed XCD subset so the B-panel stays L2-resident.
// Inner index col-major: 8 consecutive blocks share one A row-tile.
// 128x128 tile, BK=32, 4 waves (2x2), 16x16x32 MFMA, global_load_lds staging.
template <typename OT>
__global__ __launch_bounds__(256) void gemm_kernel(const bf16_t* __restrict__ A,
                                                   const bf16_t* __restrict__ Bt,
                                                   OT* __restrict__ partial,
                                                   int K, int ldc, int kLen,
                                                   int GY, int KC) {
  __shared__ __align__(16) bf16_t As[128 * 32];
  __shared__ __align__(16) bf16_t Bs[128 * 32];
  const int wgid = blockIdx.x;
  const int zc = wgid % KC;          // K-chunk == XCD (mod 8)
  const int inner = wgid / KC;
  const int by = inner % GY;         // col tile (fast)
  const int bx = inner / GY;         // row tile (slow: A row-tile L2-hot)
  const int t = threadIdx.x;
  const int lane = t & 63;
  const int wid = t >> 6;
  const int row0 = bx * 128;
  const int col0 = by * 128;
  const int kOff = zc * kLen;

  f32x4 acc[4][4] = {};

  const int rA = t >> 2;       // row within tile
  const int sA = t & 3;        // 8-elem K segment
  const bf16_t* aSrc1 = A + (size_t)(row0 + rA) * K + sA * 8 + kOff;
  const bf16_t* aSrc2 = A + (size_t)(row0 + rA + 64) * K + sA * 8 + kOff;
  const bf16_t* bSrc1 = Bt + (size_t)(col0 + rA) * K + sA * 8 + kOff;
  const bf16_t* bSrc2 = Bt + (size_t)(col0 + rA + 64) * K + sA * 8 + kOff;
  char* AsB = (char*)&As[0];
  char* BsB = (char*)&Bs[0];
  const int ldsOff1 = (wid * 64) * 16;
  const int ldsOff2 = (wid * 64 + 256) * 16;

  const int wm = wid >> 1;
  const int wn = wid & 1;
  const int lr = lane & 15;
  const int lk16 = (lane >> 4) * 16;
  int aOff[4], bOff[4];
#pragma unroll
  for (int m = 0; m < 4; ++m) aOff[m] = (wm * 64 + m * 16 + lr) * 64 + lk16;
#pragma unroll
  for (int n = 0; n < 4; ++n) bOff[n] = (wn * 64 + n * 16 + lr) * 64 + lk16;

  for (int k0 = 0; k0 < kLen; k0 += 32) {
    gload16(aSrc1 + k0, AsB + ldsOff1);
    gload16(aSrc2 + k0, AsB + ldsOff2);
    gload16(bSrc1 + k0, BsB + ldsOff1);
    gload16(bSrc2 + k0, BsB + ldsOff2);
    __syncthreads();  // drains vmcnt: LDS tiles ready
    bf16x8 af[4], bfv[4];
#pragma unroll
    for (int m = 0; m < 4; ++m) af[m] = *(const bf16x8*)(AsB + aOff[m]);
#pragma unroll
    for (int n = 0; n < 4; ++n) bfv[n] = *(const bf16x8*)(BsB + bOff[n]);
#pragma unroll
    for (int m = 0; m < 4; ++m)
#pragma unroll
      for (int n = 0; n < 4; ++n)
        acc[m][n] = __builtin_amdgcn_mfma_f32_16x16x32_bf16(af[m], bfv[n], acc[m][n], 0, 0, 0);
    __syncthreads();
  }

  // C/D layout: col = lane&15, row = (lane>>4)*4 + reg  [m89-verified]
  OT* out = partial + (size_t)zc * MPAD * ldc;
  const int crow = (lane >> 4) * 4;
  const int ccol = lane & 15;
#pragma unroll
  for (int n = 0; n < 4; ++n) {
    const int col = col0 + wn * 64 + n * 16 + ccol;
#pragma unroll
    for (int m = 0; m < 4; ++m) {
      const int rowb = row0 + wm * 64 + m * 16 + crow;
#pragma unroll
      for (int j = 0; j < 4; ++j) {
        out[(size_t)(rowb + j) * ldc + col] = (OT)acc[m][n][j];
      }
    }
  }
}

// ---------------- split-K reduce (bf16 partials): out = relu(sum + bias) -> bf16 ----------------
__global__ __launch_bounds__(256) void reduce8_kernel(const bf16_t* __restrict__ partial,
                                                      const float* __restrict__ bias,
                                                      bf16_t* __restrict__ out,
                                                      int ldc, int KC) {
  const size_t idx8 = ((size_t)blockIdx.x * 256 + threadIdx.x) * 8;  // over MPAD*ldc
  const size_t stride = (size_t)MPAD * ldc;
  float s[8] = {};
  for (int c = 0; c < KC; ++c) {
    const bf16x8 v = *(const bf16x8*)(partial + c * stride + idx8);
#pragma unroll
    for (int j = 0; j < 8; ++j) s[j] += (float)v[j];
  }
  const int col = (int)(idx8 & (size_t)(ldc - 1));  // ldc pow2, >= 8-aligned
  const f32x4 b0 = *(const f32x4*)(bias + col);
  const f32x4 b1 = *(const f32x4*)(bias + col + 4);
  bf16x8 o;
#pragma unroll
  for (int j = 0; j < 4; ++j) o[j] = (bf16_t)fmaxf(s[j] + b0[j], 0.0f);
#pragma unroll
  for (int j = 0; j < 4; ++j) o[4 + j] = (bf16_t)fmaxf(s[4 + j] + b1[j], 0.0f);
  *(bf16x8*)(out + idx8) = o;
}

// ---------------- split-K reduce (f32 partials): out = sum + bias (f32) ----------------
__global__ __launch_bounds__(256) void reduce4_kernel(const float* __restrict__ partial,
                                                      const float* __restrict__ bias,
                                                      float* __restrict__ out,
                                                      int ldc, int KC) {
  const size_t idx4 = ((size_t)blockIdx.x * 256 + threadIdx.x) * 4;
  f32x4 s = *(const f32x4*)(partial + idx4);
  const size_t stride = (size_t)MPAD * ldc;
  for (int c = 1; c < KC; ++c) s += *(const f32x4*)(partial + c * stride + idx4);
  const int col = (int)(idx4 & (size_t)(ldc - 1));
  s += *(const f32x4*)(bias + col);
  *(f32x4*)(out + idx4) = s;
}

// ---------------- row softmax stats: one wave per row ----------------
__global__ __launch_bounds__(256) void rowsm_kernel(const float* __restrict__ ho,
                                                    float* __restrict__ mxv,
                                                    float* __restrict__ invv) {
  const int row = blockIdx.x * 4 + (threadIdx.x >> 6);
  const int lane = threadIdx.x & 63;
  if (row >= M_) return;
  const float* r = ho + (size_t)row * HOUT;
  float v1 = (lane < NCLS) ? r[lane] : -3.0e38f;
  float v2 = (lane + 64 < NCLS) ? r[lane + 64] : -3.0e38f;
  float mx = fmaxf(v1, v2);
#pragma unroll
  for (int off = 32; off; off >>= 1) mx = fmaxf(mx, __shfl_xor(mx, off));
  float s = ((lane < NCLS) ? expf(v1 - mx) : 0.0f) + ((lane + 64 < NCLS) ? expf(v2 - mx) : 0.0f);
#pragma unroll
  for (int off = 32; off; off >>= 1) s += __shfl_xor(s, off);
  if (lane == 0) { mxv[row] = mx; invv[row] = 1.0f / s; }
}

// ---------------- decode + NMS prep: one thread per (roi, class) ----------------
__global__ __launch_bounds__(256) void decode_kernel(const float* __restrict__ ho,
                                                     const float* __restrict__ mxv,
                                                     const float* __restrict__ invv,
                                                     const float* __restrict__ props,
                                                     float* __restrict__ boxes,
                                                     float* __restrict__ scores,
                                                     float* __restrict__ swork,
                                                     float* __restrict__ boff,
                                                     float* __restrict__ area) {
  const int idx = blockIdx.x * 256 + threadIdx.x;
  if (idx >= M_ * 90) return;
  const int n = idx / 90;
  const int k = idx - n * 90 + 1;   // class 1..90
  const float* row = ho + (size_t)n * HOUT;
  const float sc = expf(row[k] - mxv[n]) * invv[n];
  const float* p = props + n * 4;
  const float px1 = p[0], py1 = p[1], px2 = p[2], py2 = p[3];
  const float pw = px2 - px1, ph = py2 - py1;
  const float pcx = px1 + 0.5f * pw, pcy = py1 + 0.5f * ph;
  const float* d = row + NCLS + 4 * k;
  const float dx = d[0] * 0.1f;
  const float dy = d[1] * 0.1f;
  const float dw = fminf(d[2] * 0.2f, BBOX_CLIPF);
  const float dh = fminf(d[3] * 0.2f, BBOX_CLIPF);
  const float cx = dx * pw + pcx, cy = dy * ph + pcy;
  const float w = pw * expf(dw), h = ph * expf(dh);
  const float bx1 = fminf(fmaxf(cx - 0.5f * w, 0.0f), IMGF);
  const float by1 = fminf(fmaxf(cy - 0.5f * h, 0.0f), IMGF);
  const float bx2 = fminf(fmaxf(cx + 0.5f * w, 0.0f), IMGF);
  const float by2 = fminf(fmaxf(cy + 0.5f * h, 0.0f), IMGF);
  const int j = idx;  // == b*90000 + n_local*90 + (k-1)
  boxes[4 * j + 0] = bx1; boxes[4 * j + 1] = by1;
  boxes[4 * j + 2] = bx2; boxes[4 * j + 3] = by2;
  scores[j] = sc;
  const float wv = bx2 - bx1, hv = by2 - by1;
  swork[j] = ((sc > 0.05f) && (wv >= 1.0f) && (hv >= 1.0f)) ? sc : NEGV;
  const float off = (float)k * (IMGF + 2.0f);
  const float ox1 = bx1 + off, oy1 = by1 + off, ox2 = bx2 + off, oy2 = by2 + off;
  boff[4 * j + 0] = ox1; boff[4 * j + 1] = oy1;
  boff[4 * j + 2] = ox2; boff[4 * j + 3] = oy2;
  area[j] = (ox2 - ox1) * (oy2 - oy1);
}

// ---------------- NMS: replicates jax.lax.scan semantics exactly ----------------
__global__ __launch_bounds__(1024) void nms_kernel(const float* __restrict__ boxes,
                                                   const float* __restrict__ scores,
                                                   float* __restrict__ swork,
                                                   const float* __restrict__ boff,
                                                   const float* __restrict__ area,
                                                   float* __restrict__ dout) {
  const int b = blockIdx.x;
  const int t = threadIdx.x;
  const float* Bx = boxes + (size_t)b * NMSM * 4;
  const float* Sc = scores + (size_t)b * NMSM;
  float* Sw = swork + (size_t)b * NMSM;
  const float* Bo = boff + (size_t)b * NMSM * 4;
  const float* Ar = area + (size_t)b * NMSM;
  float* dets = dout + b * (DET_ * 5);
  float* labels = dout + B_ * DET_ * 5 + b * DET_;
  __shared__ float s_val[1024];
  __shared__ int s_idx[1024];
  __shared__ float s_box[4];
  __shared__ float s_area;
  __shared__ int s_ok;
  for (int it = 0; it < DET_; ++it) {
    float bv = -3.0e38f;
    int bi = 0;
    for (int j = t; j < NMSM; j += 1024) {
      float v = Sw[j];
      if (v > bv) { bv = v; bi = j; }
    }
    s_val[t] = bv;
    s_idx[t] = bi;
    __syncthreads();
    for (int off = 512; off > 0; off >>= 1) {
      if (t < off) {
        float v2 = s_val[t + off]; int i2 = s_idx[t + off];
        if (v2 > s_val[t] || (v2 == s_val[t] && i2 < s_idx[t])) { s_val[t] = v2; s_idx[t] = i2; }
      }
      __syncthreads();
    }
    if (t == 0) {
      int i = s_idx[0];
      int ok = (s_val[0] > NEGV * 0.5f) ? 1 : 0;
      s_ok = ok;
      if (ok) {
        dets[it * 5 + 0] = Bx[i * 4 + 0];
        dets[it * 5 + 1] = Bx[i * 4 + 1];
        dets[it * 5 + 2] = Bx[i * 4 + 2];
        dets[it * 5 + 3] = Bx[i * 4 + 3];
        dets[it * 5 + 4] = Sc[i];
        labels[it] = (float)(i % 90 + 1);
        s_box[0] = Bo[i * 4 + 0]; s_box[1] = Bo[i * 4 + 1];
        s_box[2] = Bo[i * 4 + 2]; s_box[3] = Bo[i * 4 + 3];
        s_area = Ar[i];
        Sw[i] = NEGV;
      }
    }
    __syncthreads();
    if (!s_ok) {
      for (int tt = it + t; tt < DET_; tt += 1024) {
        dets[tt * 5 + 0] = 0.0f; dets[tt * 5 + 1] = 0.0f; dets[tt * 5 + 2] = 0.0f;
        dets[tt * 5 + 3] = 0.0f; dets[tt * 5 + 4] = 0.0f;
        labels[tt] = -1.0f;
      }
      return;
    }
    const float bx1 = s_box[0], by1 = s_box[1], bx2 = s_box[2], by2 = s_box[3], ai = s_area;
    for (int j = t; j < NMSM; j += 1024) {
      float v = Sw[j];
      if (v <= NEGV * 0.5f) continue;
      float ix1 = fmaxf(bx1, Bo[j * 4 + 0]);
      float iy1 = fmaxf(by1, Bo[j * 4 + 1]);
      float ix2 = fminf(bx2, Bo[j * 4 + 2]);
      float iy2 = fminf(by2, Bo[j * 4 + 3]);
      float inter = fmaxf(ix2 - ix1, 0.0f) * fmaxf(iy2 - iy1, 0.0f);
      float iou = inter / (ai + Ar[j] - inter + 1e-9f);
      if (iou > 0.5f) Sw[j] = NEGV;
    }
    __syncthreads();
  }
}

// ---------------- launch ----------------
extern "C" void kernel_launch(void* const* d_in, const int* in_sizes, int n_in,
                              void* d_out, int out_size, void* d_ws, size_t ws_size,
                              hipStream_t stream) {
  const float* features  = (const float*)d_in[0];
  const float* proposals = (const float*)d_in[1];
  const float* w1   = (const float*)d_in[2];
  const float* b1   = (const float*)d_in[3];
  const float* w2   = (const float*)d_in[4];
  const float* b2   = (const float*)d_in[5];
  const float* wcls = (const float*)d_in[6];
  const float* bcls = (const float*)d_in[7];
  const float* wbb  = (const float*)d_in[8];
  const float* bbb  = (const float*)d_in[9];
  (void)in_sizes; (void)n_in; (void)out_size;

  char* p = (char*)d_ws;
  auto alloc = [&](size_t bytes) {
    char* r = p;
    p += (bytes + 255) & ~(size_t)255;
    return r;
  };
  bf16_t* A      = (bf16_t*)alloc((size_t)MPAD * DIN * 2);
  bf16_t* w1t    = (bf16_t*)alloc((size_t)REP_ * DIN * 2);
  bf16_t* w2t    = (bf16_t*)alloc((size_t)REP_ * REP_ * 2);
  bf16_t* wht    = (bf16_t*)alloc((size_t)HOUT * REP_ * 2);
  float*  biash  = (float*)alloc((size_t)HOUT * 4);
  bf16_t* h1     = (bf16_t*)alloc((size_t)MPAD * REP_ * 2);
  bf16_t* h2     = (bf16_t*)alloc((size_t)MPAD * REP_ * 2);
  float*  ho     = (float*)alloc((size_t)MPAD * HOUT * 4);
  float*  mxv    = (float*)alloc((size_t)M_ * 4);
  float*  invv   = (float*)alloc((size_t)M_ * 4);
  float*  boxes  = (float*)alloc((size_t)B_ * NMSM * 4 * 4);
  float*  scoresb= (float*)alloc((size_t)B_ * NMSM * 4);
  float*  sworkb = (float*)alloc((size_t)B_ * NMSM * 4);
  float*  boffb  = (float*)alloc((size_t)B_ * NMSM * 4 * 4);
  float*  areab  = (float*)alloc((size_t)B_ * NMSM * 4);

  // split-K partial buffer: everything that's left (deterministic per-harness)
  size_t used = (size_t)(p - (char*)d_ws);
  size_t avail = (ws_size > used) ? (ws_size - used) : 0;
  bf16_t* partialH = (bf16_t*)p;   // bf16 partials for FC1/FC2
  float*  partialF = (float*)p;    // f32 partials for FC3 (same region, stream-ordered)
  const size_t chunkH = (size_t)MPAD * REP_ * 2;   // 4 MB (bf16, ldc=1024)
  const size_t chunkF = (size_t)MPAD * HOUT * 4;   // 4 MB (f32, ldc=512)
  int KC1 = 8;
  while (KC1 > 1 && (size_t)KC1 * chunkH > avail) KC1 >>= 1;
  int KC2 = 4;
  while (KC2 > 1 && (size_t)KC2 * chunkH > avail) KC2 >>= 1;
  int KC3 = 4;
  while (KC3 > 1 && (size_t)KC3 * chunkF > avail) KC3 >>= 1;

  roi_kernel<<<MPAD * ROISEG, 256, 0, stream>>>(features, proposals, A);
  transpose_kernel<<<dim3(DIN / 32, REP_ / 32), 256, 0, stream>>>(w1, w1t, DIN, REP_);
  transpose_kernel<<<dim3(REP_ / 32, REP_ / 32), 256, 0, stream>>>(w2, w2t, REP_, REP_);
  headw_kernel<<<(HOUT * REP_) / 256, 256, 0, stream>>>(wcls, wbb, wht);
  headb_kernel<<<1, HOUT, 0, stream>>>(bcls, bbb, biash);

  // FC1: [2048 x 12544] @ [12544 x 1024] -> h1 (relu, bf16)
  gemm_kernel<bf16_t><<<(MPAD / 128) * (REP_ / 128) * KC1, 256, 0, stream>>>(
      A, w1t, partialH, DIN, REP_, DIN / KC1, REP_ / 128, KC1);
  reduce8_kernel<<<(MPAD * REP_ / 8) / 256, 256, 0, stream>>>(partialH, b1, h1, REP_, KC1);
  // FC2: [2048 x 1024] @ [1024 x 1024] -> h2 (relu, bf16)
  gemm_kernel<bf16_t><<<(MPAD / 128) * (REP_ / 128) * KC2, 256, 0, stream>>>(
      h1, w2t, partialH, REP_, REP_, REP_ / KC2, REP_ / 128, KC2);
  reduce8_kernel<<<(MPAD * REP_ / 8) / 256, 256, 0, stream>>>(partialH, b2, h2, REP_, KC2);
  // FC3 (heads): [2048 x 1024] @ [1024 x 512] -> ho (f32)
  gemm_kernel<float><<<(MPAD / 128) * (HOUT / 128) * KC3, 256, 0, stream>>>(
      h2, wht, partialF, REP_, HOUT, REP_ / KC3, HOUT / 128, KC3);
  reduce4_kernel<<<(MPAD * HOUT / 4) / 256, 256, 0, stream>>>(partialF, biash, ho, HOUT, KC3);

  rowsm_kernel<<<(M_ + 3) / 4, 256, 0, stream>>>(ho, mxv, invv);
  decode_kernel<<<(M_ * 90 + 255) / 256, 256, 0, stream>>>(ho, mxv, invv, proposals,
                                                           boxes, scoresb, sworkb, boffb, areab);
  nms_kernel<<<B_, 1024, 0, stream>>>(boxes, scoresb, sworkb, boffb, areab, (float*)d_out);
}

// Round 6
// 240.406 us; speedup vs baseline: 1.0557x; 1.0557x over previous
//
#include <hip/hip_runtime.h>
#include <stdint.h>

// ---------------- problem constants (hard-coded from reference) ----------------
#define B_    2
#define N_    1000
#define C_    256
#define H_    50
#define W_    50
#define P_    7
#define NCLS  91
#define REP_  1024
#define DIN   (C_ * P_ * P_)   // 12544
#define M_    (B_ * N_)        // 2000
#define MPAD  2048
#define HOUT  512              // padded head cols (91 cls + 364 bbox = 455 real)
#define DET_  100
#define NMSM  (N_ * 90)        // 90000 candidates per batch
#define NEGV  (-1000000000.0f)
#define SCALE_ 0.0625f
#define IMGF  800.0f
#define BBOX_CLIPF 4.135166556742356f  // log(1000/16)

#define ROISEG 7               // blocks per roi row; 12544/7 = 1792 = 7*256
#define SEGLEN 1792

typedef __bf16 bf16_t;
typedef __attribute__((ext_vector_type(8))) __bf16 bf16x8;
typedef __attribute__((ext_vector_type(4))) __bf16 bf16x4;
typedef __attribute__((ext_vector_type(4))) float f32x4;
typedef __attribute__((ext_vector_type(4))) int i32x4;

// async global->LDS, 16B per lane. LDS dest must be wave-uniform base (+lane*16 by HW).
__device__ __forceinline__ void gload16(const void* g, void* l) {
  auto gp = (const __attribute__((address_space(1))) uint32_t*)(uintptr_t)g;
  auto lp = (__attribute__((address_space(3))) uint32_t*)(uint32_t)(uintptr_t)l;
  __builtin_amdgcn_global_load_lds(gp, lp, 16, 0, 0);
}

// ---------------- ROI align -> A bf16 [MPAD][DIN] (rows >= 2000 zeroed) ----------------
__global__ __launch_bounds__(256) void roi_kernel(const float* __restrict__ features,
                                                  const float* __restrict__ proposals,
                                                  bf16_t* __restrict__ A) {
  const int blk = blockIdx.x;
  const int n = blk / ROISEG;
  const int seg = blk - n * ROISEG;
  const int t = threadIdx.x;
  bf16_t* aseg = A + (size_t)n * DIN + seg * SEGLEN;
  if (n >= M_) {
    if (t < SEGLEN / 8) ((f32x4*)aseg)[t] = f32x4{0.f, 0.f, 0.f, 0.f};
    return;
  }
  __shared__ __align__(16) int   s_o[49][4];  // o00,o01,o10,o11 (feature-plane offsets)
  __shared__ __align__(16) float s_w[49][4];  // w00,w01,w10,w11
  __shared__ __align__(16) bf16_t s_out[SEGLEN];
  if (t < 49) {
    const float* p = proposals + n * 4;
    const int py = t / 7, px = t - (t / 7) * 7;
    float y1 = p[1] * SCALE_, y2 = p[3] * SCALE_;
    float bh = (y2 - y1) * (1.0f / 7.0f);
    float y = y1 + ((float)py + 0.5f) * bh - 0.5f;
    y = fminf(fmaxf(y, 0.0f), 49.0f);
    int y0 = (int)floorf(y);
    int y1i = min(y0 + 1, 49);
    float ly = y - (float)y0, hy = 1.0f - ly;
    float x1 = p[0] * SCALE_, x2 = p[2] * SCALE_;
    float bw = (x2 - x1) * (1.0f / 7.0f);
    float x = x1 + ((float)px + 0.5f) * bw - 0.5f;
    x = fminf(fmaxf(x, 0.0f), 49.0f);
    int x0 = (int)floorf(x);
    int x1i = min(x0 + 1, 49);
    float lx = x - (float)x0, hx = 1.0f - lx;
    s_o[t][0] = y0 * W_ + x0;
    s_o[t][1] = y0 * W_ + x1i;
    s_o[t][2] = y1i * W_ + x0;
    s_o[t][3] = y1i * W_ + x1i;
    s_w[t][0] = hy * hx;
    s_w[t][1] = hy * lx;
    s_w[t][2] = ly * hx;
    s_w[t][3] = ly * lx;
  }
  __syncthreads();
  const int b = (n >= N_) ? 1 : 0;
  const float* fb = features + (size_t)b * (C_ * H_ * W_);
  int e0 = seg * SEGLEN + t;
  int c = e0 / 49;
  int pp = e0 - c * 49;
#pragma unroll
  for (int j = 0; j < ROISEG; ++j) {
    const i32x4 ov = *(const i32x4*)&s_o[pp][0];
    const f32x4 wv = *(const f32x4*)&s_w[pp][0];
    const float* fc = fb + c * (H_ * W_);
    float v = fc[ov[0]] * wv[0] + fc[ov[1]] * wv[1] + fc[ov[2]] * wv[2] + fc[ov[3]] * wv[3];
    s_out[j * 256 + t] = (bf16_t)v;
    pp += 11;
    c += 5;
    if (pp >= 49) { pp -= 49; c += 1; }
  }
  __syncthreads();
  if (t < SEGLEN / 8) ((f32x4*)aseg)[t] = ((const f32x4*)s_out)[t];
}

// ---------------- transpose+convert: in f32 [K][N] -> out bf16 [N][K] ----------------
__global__ __launch_bounds__(256) void transpose_kernel(const float* __restrict__ in,
                                                        bf16_t* __restrict__ out,
                                                        int K, int N) {
  __shared__ float tile[32][33];
  const int k0 = blockIdx.x * 32;
  const int n0 = blockIdx.y * 32;
  const int tx = threadIdx.x & 31;
  const int ty = threadIdx.x >> 5;  // 0..7
#pragma unroll
  for (int j = 0; j < 4; ++j) {
    int ky = ty + j * 8;
    tile[ky][tx] = in[(size_t)(k0 + ky) * N + n0 + tx];
  }
  __syncthreads();
  const int qx = threadIdx.x & 7;   // k quad
  const int ny = threadIdx.x >> 3;  // 0..31
  bf16x4 o;
#pragma unroll
  for (int i = 0; i < 4; ++i) o[i] = (bf16_t)tile[4 * qx + i][ny];
  *(bf16x4*)(&out[(size_t)(n0 + ny) * K + k0 + 4 * qx]) = o;
}

// ---------------- build concat head weight (B^T) and bias ----------------
__global__ __launch_bounds__(256) void headw_kernel(const float* __restrict__ wcls,
                                                    const float* __restrict__ wbb,
                                                    bf16_t* __restrict__ wht) {
  int idx = blockIdx.x * 256 + threadIdx.x;  // HOUT*REP_ total
  int j = idx >> 10;        // output column (row of B^T), 0..511
  int k = idx & 1023;
  float v = 0.0f;
  if (j < NCLS) v = wcls[(size_t)k * NCLS + j];
  else if (j < 455) v = wbb[(size_t)k * 364 + (j - NCLS)];
  wht[idx] = (bf16_t)v;
}

__global__ void headb_kernel(const float* __restrict__ bcls,
                             const float* __restrict__ bbb,
                             float* __restrict__ biash) {
  int j = threadIdx.x;  // 512
  float v = 0.0f;
  if (j < NCLS) v = bcls[j];
  else if (j < 455) v = bbb[j - NCLS];
  biash[j] = v;
}

// ---------------- FC1: 256x256-tile deep-pipelined MFMA GEMM (8-wave, split-K) ----------------
// 3 K-tile LDS buffers (32-deep each), depth-2 prefetch with counted vmcnt(4),
// st_16x32 XOR swizzle (byte ^= ((byte>>9)&1)<<5) applied on pre-swizzled
// global source (gload_lds writes linearly) and on swizzled ds_read offsets.
// Grid: KC * 32 blocks (M/256=8 x N/256=4), 512 threads, 1 block/CU.
__global__ __launch_bounds__(512, 2) void gemm8_kernel(const bf16_t* __restrict__ A,
                                                       const bf16_t* __restrict__ Bt,
                                                       float* __restrict__ partial,
                                                       int K, int kLen) {
  __shared__ __align__(16) bf16_t lds[3 * 2 * 2 * 128 * 32];  // 96 KiB
  const int t = threadIdx.x;
  const int lane = t & 63;
  const int w = t >> 6;         // 0..7
  const int wm = w >> 2;        // 0..1  (A-half / M region)
  const int wn = w & 3;         // 0..3  (64-col strip)
  const int bid = blockIdx.x;
  const int zc = bid >> 5;      // K-chunk
  const int inner = bid & 31;
  const int row0 = (inner >> 2) * 256;
  const int col0 = (inner & 3) * 256;
  const int kOff = zc * kLen;
  const int G = kLen >> 5;      // 32-deep K-tiles

  // frag read byte-offsets within an 8KB half (st_16x32 swizzled)
  const int lr = lane & 15;
  const int kb = (lane >> 4) * 16;
  int aoff[8], boff[4];
#pragma unroll
  for (int m = 0; m < 8; ++m) {
    int r = m * 16 + lr;
    aoff[m] = (r * 64 + kb) ^ (((r >> 3) & 1) << 5);
  }
#pragma unroll
  for (int n = 0; n < 4; ++n) {
    int r = (wn & 1) * 64 + n * 16 + lr;
    boff[n] = (r * 64 + kb) ^ (((r >> 3) & 1) << 5);
  }

  // staging source (per-thread; source pre-swizzled so linear LDS dest ends up swizzled)
  const int s_row = t >> 2;                                  // 0..127 within half
  const int s_k8 = (t & 3) ^ (((s_row >> 3) & 1) << 1);      // 8-elem K group
  const bf16_t* pAs = A + (size_t)(row0 + s_row) * K + kOff + s_k8 * 8;
  const bf16_t* pBs = Bt + (size_t)(col0 + s_row) * K + kOff + s_k8 * 8;
  const size_t halfStride = (size_t)128 * K;
  char* ldsBase = (char*)&lds[0];
  const int wOff = w << 10;  // wave-uniform chunk base (HW adds lane*16)

  auto stage = [&](int buf, int hp, int kt) {
    const bf16_t* src = ((hp < 2) ? pAs : pBs) + (size_t)(hp & 1) * halfStride + kt * 32;
    char* dst = ldsBase + buf * 32768 + (hp >> 1) * 16384 + (hp & 1) * 8192 + wOff;
    gload16(src, dst);
  };

  f32x4 acc[8][4] = {};

  // prologue: kt0 -> buf0, kt1 -> buf1 (8 loads); kt0 guaranteed complete
#pragma unroll
  for (int hp = 0; hp < 4; ++hp) stage(0, hp, 0);
#pragma unroll
  for (int hp = 0; hp < 4; ++hp) stage(1, hp, 1);
  asm volatile("s_waitcnt vmcnt(4)" ::: "memory");
  __builtin_amdgcn_s_barrier();
  __builtin_amdgcn_sched_barrier(0);

  for (int g = 0; g < G; ++g) {
    const int cb = g % 3;          // compute buffer (kt g)
    const int sb = (g + 2) % 3;    // stage buffer (kt g+2)
    const bool doStage = (g + 2) < G;
    char* lA = ldsBase + cb * 32768 + wm * 8192;
    char* lB = ldsBase + cb * 32768 + 16384 + (wn >> 1) * 8192;
#pragma unroll
    for (int q = 0; q < 4; ++q) {    // 4 phases: C-quadrants (mh,nh)
      const int mh = q >> 1, nh = q & 1;
      bf16x8 af[4], bfv[2];
#pragma unroll
      for (int i = 0; i < 4; ++i) af[i] = *(const bf16x8*)(lA + aoff[mh * 4 + i]);
#pragma unroll
      for (int j2 = 0; j2 < 2; ++j2) bfv[j2] = *(const bf16x8*)(lB + boff[nh * 2 + j2]);
      if (doStage) stage(sb, q, g + 2);
      if (q == 3) asm volatile("s_waitcnt vmcnt(4)" ::: "memory");  // kt g+1 complete
      __builtin_amdgcn_s_barrier();
      __builtin_amdgcn_sched_barrier(0);
      __builtin_amdgcn_s_setprio(1);
#pragma unroll
      for (int i = 0; i < 4; ++i)
#pragma unroll
        for (int j2 = 0; j2 < 2; ++j2)
          acc[mh * 4 + i][nh * 2 + j2] = __builtin_amdgcn_mfma_f32_16x16x32_bf16(
              af[i], bfv[j2], acc[mh * 4 + i][nh * 2 + j2], 0, 0, 0);
      __builtin_amdgcn_s_setprio(0);
      __builtin_amdgcn_s_barrier();
      __builtin_amdgcn_sched_barrier(0);
    }
  }

  // epilogue: f32 partial write. C/D: col=lane&15, row=(lane>>4)*4+reg
  float* out = partial + (size_t)zc * MPAD * REP_;
  const int crow = (lane >> 4) * 4;
#pragma unroll
  for (int n = 0; n < 4; ++n) {
    const int col = col0 + wn * 64 + n * 16 + lr;
#pragma unroll
    for (int m = 0; m < 8; ++m) {
      const int rowb = row0 + wm * 128 + m * 16 + crow;
#pragma unroll
      for (int j2 = 0; j2 < 4; ++j2)
        out[(size_t)(rowb + j2) * REP_ + col] = acc[m][n][j2];
    }
  }
}

// ---------------- FC2/FC3: 128x128-tile 2-phase GEMM, split-K (R4 config) ----------------
__global__ __launch_bounds__(256) void gemm_kernel(const bf16_t* __restrict__ A,
                                                   const bf16_t* __restrict__ Bt,
                                                   float* __restrict__ partial,
                                                   int K, int ldc, int kLen) {
  __shared__ __align__(16) bf16_t As[128 * 32];
  __shared__ __align__(16) bf16_t Bs[128 * 32];
  const int t = threadIdx.x;
  const int lane = t & 63;
  const int wid = t >> 6;
  const int row0 = blockIdx.x * 128;
  const int col0 = blockIdx.y * 128;
  const int kOff = blockIdx.z * kLen;

  f32x4 acc[4][4] = {};

  const int rA = t >> 2;
  const int sA = t & 3;
  const bf16_t* aSrc1 = A + (size_t)(row0 + rA) * K + sA * 8 + kOff;
  const bf16_t* aSrc2 = A + (size_t)(row0 + rA + 64) * K + sA * 8 + kOff;
  const bf16_t* bSrc1 = Bt + (size_t)(col0 + rA) * K + sA * 8 + kOff;
  const bf16_t* bSrc2 = Bt + (size_t)(col0 + rA + 64) * K + sA * 8 + kOff;
  char* AsB = (char*)&As[0];
  char* BsB = (char*)&Bs[0];
  const int ldsOff1 = (wid * 64) * 16;
  const int ldsOff2 = (wid * 64 + 256) * 16;

  const int wm = wid >> 1;
  const int wn = wid & 1;
  const int lr = lane & 15;
  const int lk16 = (lane >> 4) * 16;
  int aOff[4], bOff[4];
#pragma unroll
  for (int m = 0; m < 4; ++m) aOff[m] = (wm * 64 + m * 16 + lr) * 64 + lk16;
#pragma unroll
  for (int n = 0; n < 4; ++n) bOff[n] = (wn * 64 + n * 16 + lr) * 64 + lk16;

  for (int k0 = 0; k0 < kLen; k0 += 32) {
    gload16(aSrc1 + k0, AsB + ldsOff1);
    gload16(aSrc2 + k0, AsB + ldsOff2);
    gload16(bSrc1 + k0, BsB + ldsOff1);
    gload16(bSrc2 + k0, BsB + ldsOff2);
    __syncthreads();
    bf16x8 af[4], bfv[4];
#pragma unroll
    for (int m = 0; m < 4; ++m) af[m] = *(const bf16x8*)(AsB + aOff[m]);
#pragma unroll
    for (int n = 0; n < 4; ++n) bfv[n] = *(const bf16x8*)(BsB + bOff[n]);
#pragma unroll
    for (int m = 0; m < 4; ++m)
#pragma unroll
      for (int n = 0; n < 4; ++n)
        acc[m][n] = __builtin_amdgcn_mfma_f32_16x16x32_bf16(af[m], bfv[n], acc[m][n], 0, 0, 0);
    __syncthreads();
  }

  float* out = partial + (size_t)blockIdx.z * MPAD * ldc;
  const int crow = (lane >> 4) * 4;
  const int ccol = lane & 15;
#pragma unroll
  for (int n = 0; n < 4; ++n) {
    const int col = col0 + wn * 64 + n * 16 + ccol;
#pragma unroll
    for (int m = 0; m < 4; ++m) {
      const int rowb = row0 + wm * 64 + m * 16 + crow;
#pragma unroll
      for (int j = 0; j < 4; ++j) {
        out[(size_t)(rowb + j) * ldc + col] = acc[m][n][j];
      }
    }
  }
}

// ---------------- split-K reduce: out = act(sum_kc partial[kc] + bias) ----------------
// mode 0: f32 out, no relu.  mode 1: relu -> bf16 out.
__global__ __launch_bounds__(256) void reduce_kernel(const float* __restrict__ partial,
                                                     const float* __restrict__ bias,
                                                     void* __restrict__ out,
                                                     int ldc, int KC, int mode) {
  const size_t idx4 = ((size_t)blockIdx.x * 256 + threadIdx.x) * 4;  // over MPAD*ldc
  f32x4 s = *(const f32x4*)(partial + idx4);
  const size_t stride = (size_t)MPAD * ldc;
  for (int c = 1; c < KC; ++c) s += *(const f32x4*)(partial + c * stride + idx4);
  const int col = (int)(idx4 & (size_t)(ldc - 1));  // ldc is a power of two
  const f32x4 bv = *(const f32x4*)(bias + col);
  s += bv;
  if (mode) {
    bf16x4 o;
#pragma unroll
    for (int j = 0; j < 4; ++j) o[j] = (bf16_t)fmaxf(s[j], 0.0f);
    *(bf16x4*)((bf16_t*)out + idx4) = o;
  } else {
    *(f32x4*)((float*)out + idx4) = s;
  }
}

// ---------------- row softmax stats: one wave per row ----------------
__global__ __launch_bounds__(256) void rowsm_kernel(const float* __restrict__ ho,
                                                    float* __restrict__ mxv,
                                                    float* __restrict__ invv) {
  const int row = blockIdx.x * 4 + (threadIdx.x >> 6);
  const int lane = threadIdx.x & 63;
  if (row >= M_) return;
  const float* r = ho + (size_t)row * HOUT;
  float v1 = (lane < NCLS) ? r[lane] : -3.0e38f;
  float v2 = (lane + 64 < NCLS) ? r[lane + 64] : -3.0e38f;
  float mx = fmaxf(v1, v2);
#pragma unroll
  for (int off = 32; off; off >>= 1) mx = fmaxf(mx, __shfl_xor(mx, off));
  float s = ((lane < NCLS) ? expf(v1 - mx) : 0.0f) + ((lane + 64 < NCLS) ? expf(v2 - mx) : 0.0f);
#pragma unroll
  for (int off = 32; off; off >>= 1) s += __shfl_xor(s, off);
  if (lane == 0) { mxv[row] = mx; invv[row] = 1.0f / s; }
}

// ---------------- decode + NMS prep: one thread per (roi, class) ----------------
__global__ __launch_bounds__(256) void decode_kernel(const float* __restrict__ ho,
                                                     const float* __restrict__ mxv,
                                                     const float* __restrict__ invv,
                                                     const float* __restrict__ props,
                                                     float* __restrict__ boxes,
                                                     float* __restrict__ scores,
                                                     float* __restrict__ swork,
                                                     float* __restrict__ boff,
                                                     float* __restrict__ area) {
  const int idx = blockIdx.x * 256 + threadIdx.x;
  if (idx >= M_ * 90) return;
  const int n = idx / 90;
  const int k = idx - n * 90 + 1;   // class 1..90
  const float* row = ho + (size_t)n * HOUT;
  const float sc = expf(row[k] - mxv[n]) * invv[n];
  const float* p = props + n * 4;
  const float px1 = p[0], py1 = p[1], px2 = p[2], py2 = p[3];
  const float pw = px2 - px1, ph = py2 - py1;
  const float pcx = px1 + 0.5f * pw, pcy = py1 + 0.5f * ph;
  const float* d = row + NCLS + 4 * k;
  const float dx = d[0] * 0.1f;
  const float dy = d[1] * 0.1f;
  const float dw = fminf(d[2] * 0.2f, BBOX_CLIPF);
  const float dh = fminf(d[3] * 0.2f, BBOX_CLIPF);
  const float cx = dx * pw + pcx, cy = dy * ph + pcy;
  const float w = pw * expf(dw), h = ph * expf(dh);
  const float bx1 = fminf(fmaxf(cx - 0.5f * w, 0.0f), IMGF);
  const float by1 = fminf(fmaxf(cy - 0.5f * h, 0.0f), IMGF);
  const float bx2 = fminf(fmaxf(cx + 0.5f * w, 0.0f), IMGF);
  const float by2 = fminf(fmaxf(cy + 0.5f * h, 0.0f), IMGF);
  const int j = idx;  // == b*90000 + n_local*90 + (k-1)
  boxes[4 * j + 0] = bx1; boxes[4 * j + 1] = by1;
  boxes[4 * j + 2] = bx2; boxes[4 * j + 3] = by2;
  scores[j] = sc;
  const float wv = bx2 - bx1, hv = by2 - by1;
  swork[j] = ((sc > 0.05f) && (wv >= 1.0f) && (hv >= 1.0f)) ? sc : NEGV;
  const float off = (float)k * (IMGF + 2.0f);
  const float ox1 = bx1 + off, oy1 = by1 + off, ox2 = bx2 + off, oy2 = by2 + off;
  boff[4 * j + 0] = ox1; boff[4 * j + 1] = oy1;
  boff[4 * j + 2] = ox2; boff[4 * j + 3] = oy2;
  area[j] = (ox2 - ox1) * (oy2 - oy1);
}

// ---------------- NMS: replicates jax.lax.scan semantics exactly ----------------
__global__ __launch_bounds__(1024) void nms_kernel(const float* __restrict__ boxes,
                                                   const float* __restrict__ scores,
                                                   float* __restrict__ swork,
                                                   const float* __restrict__ boff,
                                                   const float* __restrict__ area,
                                                   float* __restrict__ dout) {
  const int b = blockIdx.x;
  const int t = threadIdx.x;
  const float* Bx = boxes + (size_t)b * NMSM * 4;
  const float* Sc = scores + (size_t)b * NMSM;
  float* Sw = swork + (size_t)b * NMSM;
  const float* Bo = boff + (size_t)b * NMSM * 4;
  const float* Ar = area + (size_t)b * NMSM;
  float* dets = dout + b * (DET_ * 5);
  float* labels = dout + B_ * DET_ * 5 + b * DET_;
  __shared__ float s_val[1024];
  __shared__ int s_idx[1024];
  __shared__ float s_box[4];
  __shared__ float s_area;
  __shared__ int s_ok;
  for (int it = 0; it < DET_; ++it) {
    float bv = -3.0e38f;
    int bi = 0;
    for (int j = t; j < NMSM; j += 1024) {
      float v = Sw[j];
      if (v > bv) { bv = v; bi = j; }
    }
    s_val[t] = bv;
    s_idx[t] = bi;
    __syncthreads();
    for (int off = 512; off > 0; off >>= 1) {
      if (t < off) {
        float v2 = s_val[t + off]; int i2 = s_idx[t + off];
        if (v2 > s_val[t] || (v2 == s_val[t] && i2 < s_idx[t])) { s_val[t] = v2; s_idx[t] = i2; }
      }
      __syncthreads();
    }
    if (t == 0) {
      int i = s_idx[0];
      int ok = (s_val[0] > NEGV * 0.5f) ? 1 : 0;
      s_ok = ok;
      if (ok) {
        dets[it * 5 + 0] = Bx[i * 4 + 0];
        dets[it * 5 + 1] = Bx[i * 4 + 1];
        dets[it * 5 + 2] = Bx[i * 4 + 2];
        dets[it * 5 + 3] = Bx[i * 4 + 3];
        dets[it * 5 + 4] = Sc[i];
        labels[it] = (float)(i % 90 + 1);
        s_box[0] = Bo[i * 4 + 0]; s_box[1] = Bo[i * 4 + 1];
        s_box[2] = Bo[i * 4 + 2]; s_box[3] = Bo[i * 4 + 3];
        s_area = Ar[i];
        Sw[i] = NEGV;
      }
    }
    __syncthreads();
    if (!s_ok) {
      for (int tt = it + t; tt < DET_; tt += 1024) {
        dets[tt * 5 + 0] = 0.0f; dets[tt * 5 + 1] = 0.0f; dets[tt * 5 + 2] = 0.0f;
        dets[tt * 5 + 3] = 0.0f; dets[tt * 5 + 4] = 0.0f;
        labels[tt] = -1.0f;
      }
      return;
    }
    const float bx1 = s_box[0], by1 = s_box[1], bx2 = s_box[2], by2 = s_box[3], ai = s_area;
    for (int j = t; j < NMSM; j += 1024) {
      float v = Sw[j];
      if (v <= NEGV * 0.5f) continue;
      float ix1 = fmaxf(bx1, Bo[j * 4 + 0]);
      float iy1 = fmaxf(by1, Bo[j * 4 + 1]);
      float ix2 = fminf(bx2, Bo[j * 4 + 2]);
      float iy2 = fminf(by2, Bo[j * 4 + 3]);
      float inter = fmaxf(ix2 - ix1, 0.0f) * fmaxf(iy2 - iy1, 0.0f);
      float iou = inter / (ai + Ar[j] - inter + 1e-9f);
      if (iou > 0.5f) Sw[j] = NEGV;
    }
    __syncthreads();
  }
}

// ---------------- launch ----------------
extern "C" void kernel_launch(void* const* d_in, const int* in_sizes, int n_in,
                              void* d_out, int out_size, void* d_ws, size_t ws_size,
                              hipStream_t stream) {
  const float* features  = (const float*)d_in[0];
  const float* proposals = (const float*)d_in[1];
  const float* w1   = (const float*)d_in[2];
  const float* b1   = (const float*)d_in[3];
  const float* w2   = (const float*)d_in[4];
  const float* b2   = (const float*)d_in[5];
  const float* wcls = (const float*)d_in[6];
  const float* bcls = (const float*)d_in[7];
  const float* wbb  = (const float*)d_in[8];
  const float* bbb  = (const float*)d_in[9];
  (void)in_sizes; (void)n_in; (void)out_size;

  char* p = (char*)d_ws;
  auto alloc = [&](size_t bytes) {
    char* r = p;
    p += (bytes + 255) & ~(size_t)255;
    return r;
  };
  bf16_t* A      = (bf16_t*)alloc((size_t)MPAD * DIN * 2);
  bf16_t* w1t    = (bf16_t*)alloc((size_t)REP_ * DIN * 2);
  bf16_t* w2t    = (bf16_t*)alloc((size_t)REP_ * REP_ * 2);
  bf16_t* wht    = (bf16_t*)alloc((size_t)HOUT * REP_ * 2);
  float*  biash  = (float*)alloc((size_t)HOUT * 4);
  bf16_t* h1     = (bf16_t*)alloc((size_t)MPAD * REP_ * 2);
  bf16_t* h2     = (bf16_t*)alloc((size_t)MPAD * REP_ * 2);
  float*  ho     = (float*)alloc((size_t)MPAD * HOUT * 4);
  float*  mxv    = (float*)alloc((size_t)M_ * 4);
  float*  invv   = (float*)alloc((size_t)M_ * 4);
  float*  boxes  = (float*)alloc((size_t)B_ * NMSM * 4 * 4);
  float*  scoresb= (float*)alloc((size_t)B_ * NMSM * 4);
  float*  sworkb = (float*)alloc((size_t)B_ * NMSM * 4);
  float*  boffb  = (float*)alloc((size_t)B_ * NMSM * 4 * 4);
  float*  areab  = (float*)alloc((size_t)B_ * NMSM * 4);

  // split-K partial buffer (f32): everything that's left
  size_t used = (size_t)(p - (char*)d_ws);
  size_t avail = (ws_size > used) ? (ws_size - used) : 0;
  float* partial = (float*)p;
  const size_t chunkB = (size_t)MPAD * REP_ * 4;   // 8 MB per chunk at ldc=1024
  int KC1 = 8;                                     // kLen must stay %32==0
  while (KC1 > 1 && (size_t)KC1 * chunkB > avail) KC1 >>= 1;
  int KC2 = 4;
  while (KC2 > 1 && (size_t)KC2 * chunkB > avail) KC2 >>= 1;
  int KC3 = 4;  // ldc=512: half the bytes, always fits if KC2 fits

  roi_kernel<<<MPAD * ROISEG, 256, 0, stream>>>(features, proposals, A);
  transpose_kernel<<<dim3(DIN / 32, REP_ / 32), 256, 0, stream>>>(w1, w1t, DIN, REP_);
  transpose_kernel<<<dim3(REP_ / 32, REP_ / 32), 256, 0, stream>>>(w2, w2t, REP_, REP_);
  headw_kernel<<<(HOUT * REP_) / 256, 256, 0, stream>>>(wcls, wbb, wht);
  headb_kernel<<<1, HOUT, 0, stream>>>(bcls, bbb, biash);

  // FC1: [2048 x 12544] @ [12544 x 1024] -> h1 (relu, bf16). 8-wave deep-pipelined kernel.
  gemm8_kernel<<<32 * KC1, 512, 0, stream>>>(A, w1t, partial, DIN, DIN / KC1);
  reduce_kernel<<<(MPAD * REP_ / 4) / 256, 256, 0, stream>>>(partial, b1, h1, REP_, KC1, 1);
  // FC2: [2048 x 1024] @ [1024 x 1024] -> h2 (relu, bf16)
  gemm_kernel<<<dim3(MPAD / 128, REP_ / 128, KC2), 256, 0, stream>>>(h1, w2t, partial, REP_, REP_, REP_ / KC2);
  reduce_kernel<<<(MPAD * REP_ / 4) / 256, 256, 0, stream>>>(partial, b2, h2, REP_, KC2, 1);
  // FC3 (heads): [2048 x 1024] @ [1024 x 512] -> ho (f32)
  gemm_kernel<<<dim3(MPAD / 128, HOUT / 128, KC3), 256, 0, stream>>>(h2, wht, partial, REP_, HOUT, REP_ / KC3);
  reduce_kernel<<<(MPAD * HOUT / 4) / 256, 256, 0, stream>>>(partial, biash, ho, HOUT, KC3, 0);

  rowsm_kernel<<<(M_ + 3) / 4, 256, 0, stream>>>(ho, mxv, invv);
  decode_kernel<<<(M_ * 90 + 255) / 256, 256, 0, stream>>>(ho, mxv, invv, proposals,
                                                           boxes, scoresb, sworkb, boffb, areab);
  nms_kernel<<<B_, 1024, 0, stream>>>(boxes, scoresb, sworkb, boffb, areab, (float*)d_out);
}

// Round 7
// 209.936 us; speedup vs baseline: 1.2090x; 1.1451x over previous
//
#include <hip/hip_runtime.h>
#include <stdint.h>

// ---------------- problem constants (hard-coded from reference) ----------------
#define B_    2
#define N_    1000
#define C_    256
#define H_    50
#define W_    50
#define P_    7
#define NCLS  91
#define REP_  1024
#define DIN   (C_ * P_ * P_)   // 12544
#define M_    (B_ * N_)        // 2000
#define MPAD  2048
#define HOUT  512              // padded head cols (91 cls + 364 bbox = 455 real)
#define DET_  100
#define NMSM  (N_ * 90)        // 90000 candidates per batch
#define NEGV  (-1000000000.0f)
#define SCALE_ 0.0625f
#define IMGF  800.0f
#define BBOX_CLIPF 4.135166556742356f  // log(1000/16)

#define RC_   25               // rois per roi-chunk (1000 % 25 == 0: no batch mixing)
#define CC_   4                // channels per channel-chunk

typedef __bf16 bf16_t;
typedef __attribute__((ext_vector_type(8))) __bf16 bf16x8;
typedef __attribute__((ext_vector_type(4))) __bf16 bf16x4;
typedef __attribute__((ext_vector_type(4))) float f32x4;

// async global->LDS, 16B per lane. LDS dest must be wave-uniform base (+lane*16 by HW).
__device__ __forceinline__ void gload16(const void* g, void* l) {
  auto gp = (const __attribute__((address_space(1))) uint32_t*)(uintptr_t)g;
  auto lp = (__attribute__((address_space(3))) uint32_t*)(uint32_t)(uintptr_t)l;
  __builtin_amdgcn_global_load_lds(gp, lp, 16, 0, 0);
}

// ---------------- ROI align v3: LDS-staged feature planes, gathers from LDS ----------------
// Block = (channel-chunk of 4 planes, roi-chunk of 25 rois). Planes staged coalesced
// into LDS (40KB); per-(roi,bin) bilinear table packed (u16 offset+flags, f32 ly/lx);
// 4 corner reads per output come from LDS instead of divergent global gathers (the
// TA-throughput bottleneck measured in R6: 1.6M wave-gathers x ~30cy == 78us).
__global__ __launch_bounds__(256) void roi_kernel(const float* __restrict__ features,
                                                  const float* __restrict__ proposals,
                                                  bf16_t* __restrict__ A) {
  const int cc0 = blockIdx.x * CC_;       // channel base (0..252)
  const int roiBase = blockIdx.y * RC_;   // roi base
  const int t = threadIdx.x;
  if (roiBase >= M_) {
    // padded rows 2000..2047: zero this block's 4-channel slice
    for (int idx = t; idx < RC_ * 49; idx += 256) {
      const int r = idx / 49, pp = idx - r * 49;
      const int n = roiBase + r;
      if (n < MPAD) {
        bf16_t* arow = A + (size_t)n * DIN + cc0 * 49 + pp;
#pragma unroll
        for (int c = 0; c < CC_; ++c) arow[c * 49] = (bf16_t)0.0f;
      }
    }
    return;
  }
  __shared__ __align__(16) float s_pl[CC_ * 2500];   // 40000 B
  __shared__ float s_ly[RC_ * 49];                   // 4900 B
  __shared__ float s_lx[RC_ * 49];                   // 4900 B
  __shared__ unsigned short s_off[RC_ * 49];         // 2450 B  (total 52.25 KB -> 3 blk/CU)
  const int b = (roiBase >= N_) ? 1 : 0;
  // stage 4 contiguous channel planes, coalesced f32x4
  const f32x4* src = (const f32x4*)(features + (size_t)(b * C_ + cc0) * (H_ * W_));
  f32x4* dst = (f32x4*)s_pl;
  for (int i = t; i < CC_ * 2500 / 4; i += 256) dst[i] = src[i];
  // bilinear tables for 25 rois x 49 bins
  for (int idx = t; idx < RC_ * 49; idx += 256) {
    const int r = idx / 49, pp = idx - r * 49;
    const int py = pp / 7, px = pp - py * 7;
    const float* p = proposals + (roiBase + r) * 4;
    float y1 = p[1] * SCALE_, y2 = p[3] * SCALE_;
    float bh = (y2 - y1) * (1.0f / 7.0f);
    float y = y1 + ((float)py + 0.5f) * bh - 0.5f;
    y = fminf(fmaxf(y, 0.0f), 49.0f);
    int y0 = (int)floorf(y);
    int dy = (y0 < 49) ? 1 : 0;        // y1i - y0
    float ly = y - (float)y0;
    float x1 = p[0] * SCALE_, x2 = p[2] * SCALE_;
    float bw = (x2 - x1) * (1.0f / 7.0f);
    float x = x1 + ((float)px + 0.5f) * bw - 0.5f;
    x = fminf(fmaxf(x, 0.0f), 49.0f);
    int x0 = (int)floorf(x);
    int dx = (x0 < 49) ? 1 : 0;        // x1i - x0
    float lx = x - (float)x0;
    s_off[idx] = (unsigned short)((y0 * W_ + x0) | (dx << 12) | (dy << 13));
    s_ly[idx] = ly;
    s_lx[idx] = lx;
  }
  __syncthreads();
  // compute: each idx = (roi, bin); 4 channels reuse the table from registers
  for (int idx = t; idx < RC_ * 49; idx += 256) {
    const int r = idx / 49, pp = idx - r * 49;
    const unsigned off = s_off[idx];
    const float ly = s_ly[idx], lx = s_lx[idx];
    const float hy = 1.0f - ly, hx = 1.0f - lx;
    const int o00 = off & 0xFFF;
    const int dx = (off >> 12) & 1;
    const int o10 = o00 + W_ * ((off >> 13) & 1);
    const float w00 = hy * hx, w01 = hy * lx, w10 = ly * hx, w11 = ly * lx;
    bf16_t* arow = A + (size_t)(roiBase + r) * DIN + cc0 * 49 + pp;
#pragma unroll
    for (int c = 0; c < CC_; ++c) {
      const float* pl = s_pl + c * 2500;
      float v = pl[o00] * w00 + pl[o00 + dx] * w01 + pl[o10] * w10 + pl[o10 + dx] * w11;
      arow[c * 49] = (bf16_t)v;
    }
  }
}

// ---------------- transpose+convert: in f32 [K][N] -> out bf16 [N][K] ----------------
__global__ __launch_bounds__(256) void transpose_kernel(const float* __restrict__ in,
                                                        bf16_t* __restrict__ out,
                                                        int K, int N) {
  __shared__ float tile[32][33];
  const int k0 = blockIdx.x * 32;
  const int n0 = blockIdx.y * 32;
  const int tx = threadIdx.x & 31;
  const int ty = threadIdx.x >> 5;  // 0..7
#pragma unroll
  for (int j = 0; j < 4; ++j) {
    int ky = ty + j * 8;
    tile[ky][tx] = in[(size_t)(k0 + ky) * N + n0 + tx];
  }
  __syncthreads();
  const int qx = threadIdx.x & 7;   // k quad
  const int ny = threadIdx.x >> 3;  // 0..31
  bf16x4 o;
#pragma unroll
  for (int i = 0; i < 4; ++i) o[i] = (bf16_t)tile[4 * qx + i][ny];
  *(bf16x4*)(&out[(size_t)(n0 + ny) * K + k0 + 4 * qx]) = o;
}

// ---------------- build concat head weight (B^T) and bias ----------------
__global__ __launch_bounds__(256) void headw_kernel(const float* __restrict__ wcls,
                                                    const float* __restrict__ wbb,
                                                    bf16_t* __restrict__ wht) {
  int idx = blockIdx.x * 256 + threadIdx.x;  // HOUT*REP_ total
  int j = idx >> 10;        // output column (row of B^T), 0..511
  int k = idx & 1023;
  float v = 0.0f;
  if (j < NCLS) v = wcls[(size_t)k * NCLS + j];
  else if (j < 455) v = wbb[(size_t)k * 364 + (j - NCLS)];
  wht[idx] = (bf16_t)v;
}

__global__ void headb_kernel(const float* __restrict__ bcls,
                             const float* __restrict__ bbb,
                             float* __restrict__ biash) {
  int j = threadIdx.x;  // 512
  float v = 0.0f;
  if (j < NCLS) v = bcls[j];
  else if (j < 455) v = bbb[j - NCLS];
  biash[j] = v;
}

// ---------------- FC1: 256x256-tile deep-pipelined MFMA GEMM (8-wave, split-K) ----------------
__global__ __launch_bounds__(512, 2) void gemm8_kernel(const bf16_t* __restrict__ A,
                                                       const bf16_t* __restrict__ Bt,
                                                       float* __restrict__ partial,
                                                       int K, int kLen) {
  __shared__ __align__(16) bf16_t lds[3 * 2 * 2 * 128 * 32];  // 96 KiB
  const int t = threadIdx.x;
  const int lane = t & 63;
  const int w = t >> 6;         // 0..7
  const int wm = w >> 2;        // 0..1  (A-half / M region)
  const int wn = w & 3;         // 0..3  (64-col strip)
  const int bid = blockIdx.x;
  const int zc = bid >> 5;      // K-chunk
  const int inner = bid & 31;
  const int row0 = (inner >> 2) * 256;
  const int col0 = (inner & 3) * 256;
  const int kOff = zc * kLen;
  const int G = kLen >> 5;      // 32-deep K-tiles

  const int lr = lane & 15;
  const int kb = (lane >> 4) * 16;
  int aoff[8], boff[4];
#pragma unroll
  for (int m = 0; m < 8; ++m) {
    int r = m * 16 + lr;
    aoff[m] = (r * 64 + kb) ^ (((r >> 3) & 1) << 5);
  }
#pragma unroll
  for (int n = 0; n < 4; ++n) {
    int r = (wn & 1) * 64 + n * 16 + lr;
    boff[n] = (r * 64 + kb) ^ (((r >> 3) & 1) << 5);
  }

  const int s_row = t >> 2;                                  // 0..127 within half
  const int s_k8 = (t & 3) ^ (((s_row >> 3) & 1) << 1);      // 8-elem K group
  const bf16_t* pAs = A + (size_t)(row0 + s_row) * K + kOff + s_k8 * 8;
  const bf16_t* pBs = Bt + (size_t)(col0 + s_row) * K + kOff + s_k8 * 8;
  const size_t halfStride = (size_t)128 * K;
  char* ldsBase = (char*)&lds[0];
  const int wOff = w << 10;  // wave-uniform chunk base (HW adds lane*16)

  auto stage = [&](int buf, int hp, int kt) {
    const bf16_t* src = ((hp < 2) ? pAs : pBs) + (size_t)(hp & 1) * halfStride + kt * 32;
    char* dst = ldsBase + buf * 32768 + (hp >> 1) * 16384 + (hp & 1) * 8192 + wOff;
    gload16(src, dst);
  };

  f32x4 acc[8][4] = {};

#pragma unroll
  for (int hp = 0; hp < 4; ++hp) stage(0, hp, 0);
#pragma unroll
  for (int hp = 0; hp < 4; ++hp) stage(1, hp, 1);
  asm volatile("s_waitcnt vmcnt(4)" ::: "memory");
  __builtin_amdgcn_s_barrier();
  __builtin_amdgcn_sched_barrier(0);

  for (int g = 0; g < G; ++g) {
    const int cb = g % 3;
    const int sb = (g + 2) % 3;
    const bool doStage = (g + 2) < G;
    char* lA = ldsBase + cb * 32768 + wm * 8192;
    char* lB = ldsBase + cb * 32768 + 16384 + (wn >> 1) * 8192;
#pragma unroll
    for (int q = 0; q < 4; ++q) {
      const int mh = q >> 1, nh = q & 1;
      bf16x8 af[4], bfv[2];
#pragma unroll
      for (int i = 0; i < 4; ++i) af[i] = *(const bf16x8*)(lA + aoff[mh * 4 + i]);
#pragma unroll
      for (int j2 = 0; j2 < 2; ++j2) bfv[j2] = *(const bf16x8*)(lB + boff[nh * 2 + j2]);
      if (doStage) stage(sb, q, g + 2);
      if (q == 3) asm volatile("s_waitcnt vmcnt(4)" ::: "memory");
      __builtin_amdgcn_s_barrier();
      __builtin_amdgcn_sched_barrier(0);
      __builtin_amdgcn_s_setprio(1);
#pragma unroll
      for (int i = 0; i < 4; ++i)
#pragma unroll
        for (int j2 = 0; j2 < 2; ++j2)
          acc[mh * 4 + i][nh * 2 + j2] = __builtin_amdgcn_mfma_f32_16x16x32_bf16(
              af[i], bfv[j2], acc[mh * 4 + i][nh * 2 + j2], 0, 0, 0);
      __builtin_amdgcn_s_setprio(0);
      __builtin_amdgcn_s_barrier();
      __builtin_amdgcn_sched_barrier(0);
    }
  }

  float* out = partial + (size_t)zc * MPAD * REP_;
  const int crow = (lane >> 4) * 4;
#pragma unroll
  for (int n = 0; n < 4; ++n) {
    const int col = col0 + wn * 64 + n * 16 + lr;
#pragma unroll
    for (int m = 0; m < 8; ++m) {
      const int rowb = row0 + wm * 128 + m * 16 + crow;
#pragma unroll
      for (int j2 = 0; j2 < 4; ++j2)
        out[(size_t)(rowb + j2) * REP_ + col] = acc[m][n][j2];
    }
  }
}

// ---------------- FC2/FC3: 128x128-tile 2-phase GEMM, split-K ----------------
__global__ __launch_bounds__(256) void gemm_kernel(const bf16_t* __restrict__ A,
                                                   const bf16_t* __restrict__ Bt,
                                                   float* __restrict__ partial,
                                                   int K, int ldc, int kLen) {
  __shared__ __align__(16) bf16_t As[128 * 32];
  __shared__ __align__(16) bf16_t Bs[128 * 32];
  const int t = threadIdx.x;
  const int lane = t & 63;
  const int wid = t >> 6;
  const int row0 = blockIdx.x * 128;
  const int col0 = blockIdx.y * 128;
  const int kOff = blockIdx.z * kLen;

  f32x4 acc[4][4] = {};

  const int rA = t >> 2;
  const int sA = t & 3;
  const bf16_t* aSrc1 = A + (size_t)(row0 + rA) * K + sA * 8 + kOff;
  const bf16_t* aSrc2 = A + (size_t)(row0 + rA + 64) * K + sA * 8 + kOff;
  const bf16_t* bSrc1 = Bt + (size_t)(col0 + rA) * K + sA * 8 + kOff;
  const bf16_t* bSrc2 = Bt + (size_t)(col0 + rA + 64) * K + sA * 8 + kOff;
  char* AsB = (char*)&As[0];
  char* BsB = (char*)&Bs[0];
  const int ldsOff1 = (wid * 64) * 16;
  const int ldsOff2 = (wid * 64 + 256) * 16;

  const int wm = wid >> 1;
  const int wn = wid & 1;
  const int lr = lane & 15;
  const int lk16 = (lane >> 4) * 16;
  int aOff[4], bOff[4];
#pragma unroll
  for (int m = 0; m < 4; ++m) aOff[m] = (wm * 64 + m * 16 + lr) * 64 + lk16;
#pragma unroll
  for (int n = 0; n < 4; ++n) bOff[n] = (wn * 64 + n * 16 + lr) * 64 + lk16;

  for (int k0 = 0; k0 < kLen; k0 += 32) {
    gload16(aSrc1 + k0, AsB + ldsOff1);
    gload16(aSrc2 + k0, AsB + ldsOff2);
    gload16(bSrc1 + k0, BsB + ldsOff1);
    gload16(bSrc2 + k0, BsB + ldsOff2);
    __syncthreads();
    bf16x8 af[4], bfv[4];
#pragma unroll
    for (int m = 0; m < 4; ++m) af[m] = *(const bf16x8*)(AsB + aOff[m]);
#pragma unroll
    for (int n = 0; n < 4; ++n) bfv[n] = *(const bf16x8*)(BsB + bOff[n]);
#pragma unroll
    for (int m = 0; m < 4; ++m)
#pragma unroll
      for (int n = 0; n < 4; ++n)
        acc[m][n] = __builtin_amdgcn_mfma_f32_16x16x32_bf16(af[m], bfv[n], acc[m][n], 0, 0, 0);
    __syncthreads();
  }

  float* out = partial + (size_t)blockIdx.z * MPAD * ldc;
  const int crow = (lane >> 4) * 4;
  const int ccol = lane & 15;
#pragma unroll
  for (int n = 0; n < 4; ++n) {
    const int col = col0 + wn * 64 + n * 16 + ccol;
#pragma unroll
    for (int m = 0; m < 4; ++m) {
      const int rowb = row0 + wm * 64 + m * 16 + crow;
#pragma unroll
      for (int j = 0; j < 4; ++j) {
        out[(size_t)(rowb + j) * ldc + col] = acc[m][n][j];
      }
    }
  }
}

// ---------------- split-K reduce: out = act(sum_kc partial[kc] + bias) ----------------
__global__ __launch_bounds__(256) void reduce_kernel(const float* __restrict__ partial,
                                                     const float* __restrict__ bias,
                                                     void* __restrict__ out,
                                                     int ldc, int KC, int mode) {
  const size_t idx4 = ((size_t)blockIdx.x * 256 + threadIdx.x) * 4;  // over MPAD*ldc
  f32x4 s = *(const f32x4*)(partial + idx4);
  const size_t stride = (size_t)MPAD * ldc;
  for (int c = 1; c < KC; ++c) s += *(const f32x4*)(partial + c * stride + idx4);
  const int col = (int)(idx4 & (size_t)(ldc - 1));  // ldc is a power of two
  const f32x4 bv = *(const f32x4*)(bias + col);
  s += bv;
  if (mode) {
    bf16x4 o;
#pragma unroll
    for (int j = 0; j < 4; ++j) o[j] = (bf16_t)fmaxf(s[j], 0.0f);
    *(bf16x4*)((bf16_t*)out + idx4) = o;
  } else {
    *(f32x4*)((float*)out + idx4) = s;
  }
}

// ---------------- row softmax stats: one wave per row ----------------
__global__ __launch_bounds__(256) void rowsm_kernel(const float* __restrict__ ho,
                                                    float* __restrict__ mxv,
                                                    float* __restrict__ invv) {
  const int row = blockIdx.x * 4 + (threadIdx.x >> 6);
  const int lane = threadIdx.x & 63;
  if (row >= M_) return;
  const float* r = ho + (size_t)row * HOUT;
  float v1 = (lane < NCLS) ? r[lane] : -3.0e38f;
  float v2 = (lane + 64 < NCLS) ? r[lane + 64] : -3.0e38f;
  float mx = fmaxf(v1, v2);
#pragma unroll
  for (int off = 32; off; off >>= 1) mx = fmaxf(mx, __shfl_xor(mx, off));
  float s = ((lane < NCLS) ? expf(v1 - mx) : 0.0f) + ((lane + 64 < NCLS) ? expf(v2 - mx) : 0.0f);
#pragma unroll
  for (int off = 32; off; off >>= 1) s += __shfl_xor(s, off);
  if (lane == 0) { mxv[row] = mx; invv[row] = 1.0f / s; }
}

// ---------------- decode + NMS prep: one thread per (roi, class) ----------------
__global__ __launch_bounds__(256) void decode_kernel(const float* __restrict__ ho,
                                                     const float* __restrict__ mxv,
                                                     const float* __restrict__ invv,
                                                     const float* __restrict__ props,
                                                     float* __restrict__ boxes,
                                                     float* __restrict__ scores,
                                                     float* __restrict__ swork,
                                                     float* __restrict__ boff,
                                                     float* __restrict__ area) {
  const int idx = blockIdx.x * 256 + threadIdx.x;
  if (idx >= M_ * 90) return;
  const int n = idx / 90;
  const int k = idx - n * 90 + 1;   // class 1..90
  const float* row = ho + (size_t)n * HOUT;
  const float sc = expf(row[k] - mxv[n]) * invv[n];
  const float* p = props + n * 4;
  const float px1 = p[0], py1 = p[1], px2 = p[2], py2 = p[3];
  const float pw = px2 - px1, ph = py2 - py1;
  const float pcx = px1 + 0.5f * pw, pcy = py1 + 0.5f * ph;
  const float* d = row + NCLS + 4 * k;
  const float dx = d[0] * 0.1f;
  const float dy = d[1] * 0.1f;
  const float dw = fminf(d[2] * 0.2f, BBOX_CLIPF);
  const float dh = fminf(d[3] * 0.2f, BBOX_CLIPF);
  const float cx = dx * pw + pcx, cy = dy * ph + pcy;
  const float w = pw * expf(dw), h = ph * expf(dh);
  const float bx1 = fminf(fmaxf(cx - 0.5f * w, 0.0f), IMGF);
  const float by1 = fminf(fmaxf(cy - 0.5f * h, 0.0f), IMGF);
  const float bx2 = fminf(fmaxf(cx + 0.5f * w, 0.0f), IMGF);
  const float by2 = fminf(fmaxf(cy + 0.5f * h, 0.0f), IMGF);
  const int j = idx;
  boxes[4 * j + 0] = bx1; boxes[4 * j + 1] = by1;
  boxes[4 * j + 2] = bx2; boxes[4 * j + 3] = by2;
  scores[j] = sc;
  const float wv = bx2 - bx1, hv = by2 - by1;
  swork[j] = ((sc > 0.05f) && (wv >= 1.0f) && (hv >= 1.0f)) ? sc : NEGV;
  const float off = (float)k * (IMGF + 2.0f);
  const float ox1 = bx1 + off, oy1 = by1 + off, ox2 = bx2 + off, oy2 = by2 + off;
  boff[4 * j + 0] = ox1; boff[4 * j + 1] = oy1;
  boff[4 * j + 2] = ox2; boff[4 * j + 3] = oy2;
  area[j] = (ox2 - ox1) * (oy2 - oy1);
}

// ---------------- NMS: replicates jax.lax.scan semantics exactly ----------------
__global__ __launch_bounds__(1024) void nms_kernel(const float* __restrict__ boxes,
                                                   const float* __restrict__ scores,
                                                   float* __restrict__ swork,
                                                   const float* __restrict__ boff,
                                                   const float* __restrict__ area,
                                                   float* __restrict__ dout) {
  const int b = blockIdx.x;
  const int t = threadIdx.x;
  const float* Bx = boxes + (size_t)b * NMSM * 4;
  const float* Sc = scores + (size_t)b * NMSM;
  float* Sw = swork + (size_t)b * NMSM;
  const float* Bo = boff + (size_t)b * NMSM * 4;
  const float* Ar = area + (size_t)b * NMSM;
  float* dets = dout + b * (DET_ * 5);
  float* labels = dout + B_ * DET_ * 5 + b * DET_;
  __shared__ float s_val[1024];
  __shared__ int s_idx[1024];
  __shared__ float s_box[4];
  __shared__ float s_area;
  __shared__ int s_ok;
  for (int it = 0; it < DET_; ++it) {
    float bv = -3.0e38f;
    int bi = 0;
    for (int j = t; j < NMSM; j += 1024) {
      float v = Sw[j];
      if (v > bv) { bv = v; bi = j; }
    }
    s_val[t] = bv;
    s_idx[t] = bi;
    __syncthreads();
    for (int off = 512; off > 0; off >>= 1) {
      if (t < off) {
        float v2 = s_val[t + off]; int i2 = s_idx[t + off];
        if (v2 > s_val[t] || (v2 == s_val[t] && i2 < s_idx[t])) { s_val[t] = v2; s_idx[t] = i2; }
      }
      __syncthreads();
    }
    if (t == 0) {
      int i = s_idx[0];
      int ok = (s_val[0] > NEGV * 0.5f) ? 1 : 0;
      s_ok = ok;
      if (ok) {
        dets[it * 5 + 0] = Bx[i * 4 + 0];
        dets[it * 5 + 1] = Bx[i * 4 + 1];
        dets[it * 5 + 2] = Bx[i * 4 + 2];
        dets[it * 5 + 3] = Bx[i * 4 + 3];
        dets[it * 5 + 4] = Sc[i];
        labels[it] = (float)(i % 90 + 1);
        s_box[0] = Bo[i * 4 + 0]; s_box[1] = Bo[i * 4 + 1];
        s_box[2] = Bo[i * 4 + 2]; s_box[3] = Bo[i * 4 + 3];
        s_area = Ar[i];
        Sw[i] = NEGV;
      }
    }
    __syncthreads();
    if (!s_ok) {
      for (int tt = it + t; tt < DET_; tt += 1024) {
        dets[tt * 5 + 0] = 0.0f; dets[tt * 5 + 1] = 0.0f; dets[tt * 5 + 2] = 0.0f;
        dets[tt * 5 + 3] = 0.0f; dets[tt * 5 + 4] = 0.0f;
        labels[tt] = -1.0f;
      }
      return;
    }
    const float bx1 = s_box[0], by1 = s_box[1], bx2 = s_box[2], by2 = s_box[3], ai = s_area;
    for (int j = t; j < NMSM; j += 1024) {
      float v = Sw[j];
      if (v <= NEGV * 0.5f) continue;
      float ix1 = fmaxf(bx1, Bo[j * 4 + 0]);
      float iy1 = fmaxf(by1, Bo[j * 4 + 1]);
      float ix2 = fminf(bx2, Bo[j * 4 + 2]);
      float iy2 = fminf(by2, Bo[j * 4 + 3]);
      float inter = fmaxf(ix2 - ix1, 0.0f) * fmaxf(iy2 - iy1, 0.0f);
      float iou = inter / (ai + Ar[j] - inter + 1e-9f);
      if (iou > 0.5f) Sw[j] = NEGV;
    }
    __syncthreads();
  }
}

// ---------------- launch ----------------
extern "C" void kernel_launch(void* const* d_in, const int* in_sizes, int n_in,
                              void* d_out, int out_size, void* d_ws, size_t ws_size,
                              hipStream_t stream) {
  const float* features  = (const float*)d_in[0];
  const float* proposals = (const float*)d_in[1];
  const float* w1   = (const float*)d_in[2];
  const float* b1   = (const float*)d_in[3];
  const float* w2   = (const float*)d_in[4];
  const float* b2   = (const float*)d_in[5];
  const float* wcls = (const float*)d_in[6];
  const float* bcls = (const float*)d_in[7];
  const float* wbb  = (const float*)d_in[8];
  const float* bbb  = (const float*)d_in[9];
  (void)in_sizes; (void)n_in; (void)out_size;

  char* p = (char*)d_ws;
  auto alloc = [&](size_t bytes) {
    char* r = p;
    p += (bytes + 255) & ~(size_t)255;
    return r;
  };
  bf16_t* A      = (bf16_t*)alloc((size_t)MPAD * DIN * 2);
  bf16_t* w1t    = (bf16_t*)alloc((size_t)REP_ * DIN * 2);
  bf16_t* w2t    = (bf16_t*)alloc((size_t)REP_ * REP_ * 2);
  bf16_t* wht    = (bf16_t*)alloc((size_t)HOUT * REP_ * 2);
  float*  biash  = (float*)alloc((size_t)HOUT * 4);
  bf16_t* h1     = (bf16_t*)alloc((size_t)MPAD * REP_ * 2);
  bf16_t* h2     = (bf16_t*)alloc((size_t)MPAD * REP_ * 2);
  float*  ho     = (float*)alloc((size_t)MPAD * HOUT * 4);
  float*  mxv    = (float*)alloc((size_t)M_ * 4);
  float*  invv   = (float*)alloc((size_t)M_ * 4);
  float*  boxes  = (float*)alloc((size_t)B_ * NMSM * 4 * 4);
  float*  scoresb= (float*)alloc((size_t)B_ * NMSM * 4);
  float*  sworkb = (float*)alloc((size_t)B_ * NMSM * 4);
  float*  boffb  = (float*)alloc((size_t)B_ * NMSM * 4 * 4);
  float*  areab  = (float*)alloc((size_t)B_ * NMSM * 4);

  size_t used = (size_t)(p - (char*)d_ws);
  size_t avail = (ws_size > used) ? (ws_size - used) : 0;
  float* partial = (float*)p;
  const size_t chunkB = (size_t)MPAD * REP_ * 4;   // 8 MB per chunk at ldc=1024
  int KC1 = 8;
  while (KC1 > 1 && (size_t)KC1 * chunkB > avail) KC1 >>= 1;
  int KC2 = 4;
  while (KC2 > 1 && (size_t)KC2 * chunkB > avail) KC2 >>= 1;
  int KC3 = 4;

  // roi grid: 64 channel-chunks x 82 roi-chunks (80 real + 2 pad-zero)
  roi_kernel<<<dim3(C_ / CC_, (MPAD + RC_ - 1) / RC_), 256, 0, stream>>>(features, proposals, A);
  transpose_kernel<<<dim3(DIN / 32, REP_ / 32), 256, 0, stream>>>(w1, w1t, DIN, REP_);
  transpose_kernel<<<dim3(REP_ / 32, REP_ / 32), 256, 0, stream>>>(w2, w2t, REP_, REP_);
  headw_kernel<<<(HOUT * REP_) / 256, 256, 0, stream>>>(wcls, wbb, wht);
  headb_kernel<<<1, HOUT, 0, stream>>>(bcls, bbb, biash);

  // FC1: [2048 x 12544] @ [12544 x 1024] -> h1 (relu, bf16). 8-wave deep-pipelined kernel.
  gemm8_kernel<<<32 * KC1, 512, 0, stream>>>(A, w1t, partial, DIN, DIN / KC1);
  reduce_kernel<<<(MPAD * REP_ / 4) / 256, 256, 0, stream>>>(partial, b1, h1, REP_, KC1, 1);
  // FC2: [2048 x 1024] @ [1024 x 1024] -> h2 (relu, bf16)
  gemm_kernel<<<dim3(MPAD / 128, REP_ / 128, KC2), 256, 0, stream>>>(h1, w2t, partial, REP_, REP_, REP_ / KC2);
  reduce_kernel<<<(MPAD * REP_ / 4) / 256, 256, 0, stream>>>(partial, b2, h2, REP_, KC2, 1);
  // FC3 (heads): [2048 x 1024] @ [1024 x 512] -> ho (f32)
  gemm_kernel<<<dim3(MPAD / 128, HOUT / 128, KC3), 256, 0, stream>>>(h2, wht, partial, REP_, HOUT, REP_ / KC3);
  reduce_kernel<<<(MPAD * HOUT / 4) / 256, 256, 0, stream>>>(partial, biash, ho, HOUT, KC3, 0);

  rowsm_kernel<<<(M_ + 3) / 4, 256, 0, stream>>>(ho, mxv, invv);
  decode_kernel<<<(M_ * 90 + 255) / 256, 256, 0, stream>>>(ho, mxv, invv, proposals,
                                                           boxes, scoresb, sworkb, boffb, areab);
  nms_kernel<<<B_, 1024, 0, stream>>>(boxes, scoresb, sworkb, boffb, areab, (float*)d_out);
}

// Round 8
// 198.963 us; speedup vs baseline: 1.2756x; 1.0552x over previous
//
#include <hip/hip_runtime.h>
#include <stdint.h>

// ---------------- problem constants (hard-coded from reference) ----------------
#define B_    2
#define N_    1000
#define C_    256
#define H_    50
#define W_    50
#define P_    7
#define NCLS  91
#define REP_  1024
#define DIN   (C_ * P_ * P_)   // 12544
#define M_    (B_ * N_)        // 2000
#define MPAD  2048
#define HOUT  512              // padded head cols (91 cls + 364 bbox = 455 real)
#define DET_  100
#define NMSM  (N_ * 90)        // 90000 candidates per batch
#define NEGV  (-1000000000.0f)
#define SCALE_ 0.0625f
#define IMGF  800.0f
#define BBOX_CLIPF 4.135166556742356f  // log(1000/16)

#define RC_   25               // rois per roi-chunk (1000 % 25 == 0: no batch mixing)
#define CC_   4                // channels per channel-chunk

typedef __bf16 bf16_t;
typedef __attribute__((ext_vector_type(8))) __bf16 bf16x8;
typedef __attribute__((ext_vector_type(4))) __bf16 bf16x4;
typedef __attribute__((ext_vector_type(4))) float f32x4;

// async global->LDS, 16B per lane. LDS dest must be wave-uniform base (+lane*16 by HW).
__device__ __forceinline__ void gload16(const void* g, void* l) {
  auto gp = (const __attribute__((address_space(1))) uint32_t*)(uintptr_t)g;
  auto lp = (__attribute__((address_space(3))) uint32_t*)(uint32_t)(uintptr_t)l;
  __builtin_amdgcn_global_load_lds(gp, lp, 16, 0, 0);
}

// ---------------- ROI align: LDS-staged feature planes, gathers from LDS ----------------
__global__ __launch_bounds__(256) void roi_kernel(const float* __restrict__ features,
                                                  const float* __restrict__ proposals,
                                                  bf16_t* __restrict__ A) {
  const int cc0 = blockIdx.x * CC_;       // channel base (0..252)
  const int roiBase = blockIdx.y * RC_;   // roi base
  const int t = threadIdx.x;
  if (roiBase >= M_) {
    for (int idx = t; idx < RC_ * 49; idx += 256) {
      const int r = idx / 49, pp = idx - r * 49;
      const int n = roiBase + r;
      if (n < MPAD) {
        bf16_t* arow = A + (size_t)n * DIN + cc0 * 49 + pp;
#pragma unroll
        for (int c = 0; c < CC_; ++c) arow[c * 49] = (bf16_t)0.0f;
      }
    }
    return;
  }
  __shared__ __align__(16) float s_pl[CC_ * 2500];   // 40000 B
  __shared__ float s_ly[RC_ * 49];
  __shared__ float s_lx[RC_ * 49];
  __shared__ unsigned short s_off[RC_ * 49];
  const int b = (roiBase >= N_) ? 1 : 0;
  const f32x4* src = (const f32x4*)(features + (size_t)(b * C_ + cc0) * (H_ * W_));
  f32x4* dst = (f32x4*)s_pl;
  for (int i = t; i < CC_ * 2500 / 4; i += 256) dst[i] = src[i];
  for (int idx = t; idx < RC_ * 49; idx += 256) {
    const int r = idx / 49, pp = idx - r * 49;
    const int py = pp / 7, px = pp - py * 7;
    const float* p = proposals + (roiBase + r) * 4;
    float y1 = p[1] * SCALE_, y2 = p[3] * SCALE_;
    float bh = (y2 - y1) * (1.0f / 7.0f);
    float y = y1 + ((float)py + 0.5f) * bh - 0.5f;
    y = fminf(fmaxf(y, 0.0f), 49.0f);
    int y0 = (int)floorf(y);
    int dy = (y0 < 49) ? 1 : 0;
    float ly = y - (float)y0;
    float x1 = p[0] * SCALE_, x2 = p[2] * SCALE_;
    float bw = (x2 - x1) * (1.0f / 7.0f);
    float x = x1 + ((float)px + 0.5f) * bw - 0.5f;
    x = fminf(fmaxf(x, 0.0f), 49.0f);
    int x0 = (int)floorf(x);
    int dx = (x0 < 49) ? 1 : 0;
    float lx = x - (float)x0;
    s_off[idx] = (unsigned short)((y0 * W_ + x0) | (dx << 12) | (dy << 13));
    s_ly[idx] = ly;
    s_lx[idx] = lx;
  }
  __syncthreads();
  for (int idx = t; idx < RC_ * 49; idx += 256) {
    const int r = idx / 49, pp = idx - r * 49;
    const unsigned off = s_off[idx];
    const float ly = s_ly[idx], lx = s_lx[idx];
    const float hy = 1.0f - ly, hx = 1.0f - lx;
    const int o00 = off & 0xFFF;
    const int dx = (off >> 12) & 1;
    const int o10 = o00 + W_ * ((off >> 13) & 1);
    const float w00 = hy * hx, w01 = hy * lx, w10 = ly * hx, w11 = ly * lx;
    bf16_t* arow = A + (size_t)(roiBase + r) * DIN + cc0 * 49 + pp;
#pragma unroll
    for (int c = 0; c < CC_; ++c) {
      const float* pl = s_pl + c * 2500;
      float v = pl[o00] * w00 + pl[o00 + dx] * w01 + pl[o10] * w10 + pl[o10 + dx] * w11;
      arow[c * 49] = (bf16_t)v;
    }
  }
}

// ---------------- transpose+convert: in f32 [K][N] -> out bf16 [N][K] ----------------
__global__ __launch_bounds__(256) void transpose_kernel(const float* __restrict__ in,
                                                        bf16_t* __restrict__ out,
                                                        int K, int N) {
  __shared__ float tile[32][33];
  const int k0 = blockIdx.x * 32;
  const int n0 = blockIdx.y * 32;
  const int tx = threadIdx.x & 31;
  const int ty = threadIdx.x >> 5;  // 0..7
#pragma unroll
  for (int j = 0; j < 4; ++j) {
    int ky = ty + j * 8;
    tile[ky][tx] = in[(size_t)(k0 + ky) * N + n0 + tx];
  }
  __syncthreads();
  const int qx = threadIdx.x & 7;
  const int ny = threadIdx.x >> 3;
  bf16x4 o;
#pragma unroll
  for (int i = 0; i < 4; ++i) o[i] = (bf16_t)tile[4 * qx + i][ny];
  *(bf16x4*)(&out[(size_t)(n0 + ny) * K + k0 + 4 * qx]) = o;
}

// ---------------- build concat head weight (B^T) and bias ----------------
__global__ __launch_bounds__(256) void headw_kernel(const float* __restrict__ wcls,
                                                    const float* __restrict__ wbb,
                                                    bf16_t* __restrict__ wht) {
  int idx = blockIdx.x * 256 + threadIdx.x;
  int j = idx >> 10;
  int k = idx & 1023;
  float v = 0.0f;
  if (j < NCLS) v = wcls[(size_t)k * NCLS + j];
  else if (j < 455) v = wbb[(size_t)k * 364 + (j - NCLS)];
  wht[idx] = (bf16_t)v;
}

__global__ void headb_kernel(const float* __restrict__ bcls,
                             const float* __restrict__ bbb,
                             float* __restrict__ biash) {
  int j = threadIdx.x;
  float v = 0.0f;
  if (j < NCLS) v = bcls[j];
  else if (j < 455) v = bbb[j - NCLS];
  biash[j] = v;
}

// ---------------- FC1: 256x256-tile deep-pipelined MFMA GEMM (8-wave, split-K) ----------------
// One-shot fragment reads (each frag read ONCE: 12 ds_read_b128 per K-tile vs 24),
// single barrier per K-tile; counted vmcnt (0 when not staging: fixes R7 latent race);
// zc = bid % KC pins each K-chunk to one XCD (round-robin dispatch) for L2 reuse.
__global__ __launch_bounds__(512, 2) void gemm8_kernel(const bf16_t* __restrict__ A,
                                                       const bf16_t* __restrict__ Bt,
                                                       float* __restrict__ partial,
                                                       int K, int kLen, int KC) {
  __shared__ __align__(16) bf16_t lds[3 * 2 * 2 * 128 * 32];  // 96 KiB
  const int t = threadIdx.x;
  const int lane = t & 63;
  const int w = t >> 6;         // 0..7
  const int wm = w >> 2;        // 0..1  (A-half / M region)
  const int wn = w & 3;         // 0..3  (64-col strip)
  const int bid = blockIdx.x;
  const int zc = bid % KC;      // K-chunk == XCD under round-robin dispatch
  const int inner = bid / KC;   // 0..31
  const int row0 = (inner >> 2) * 256;
  const int col0 = (inner & 3) * 256;
  const int kOff = zc * kLen;
  const int G = kLen >> 5;      // 32-deep K-tiles

  const int lr = lane & 15;
  const int kb = (lane >> 4) * 16;
  int aoff[8], boff[4];
#pragma unroll
  for (int m = 0; m < 8; ++m) {
    int r = m * 16 + lr;
    aoff[m] = (r * 64 + kb) ^ (((r >> 3) & 1) << 5);
  }
#pragma unroll
  for (int n = 0; n < 4; ++n) {
    int r = (wn & 1) * 64 + n * 16 + lr;
    boff[n] = (r * 64 + kb) ^ (((r >> 3) & 1) << 5);
  }

  const int s_row = t >> 2;
  const int s_k8 = (t & 3) ^ (((s_row >> 3) & 1) << 1);
  const bf16_t* pAs = A + (size_t)(row0 + s_row) * K + kOff + s_k8 * 8;
  const bf16_t* pBs = Bt + (size_t)(col0 + s_row) * K + kOff + s_k8 * 8;
  const size_t halfStride = (size_t)128 * K;
  char* ldsBase = (char*)&lds[0];
  const int wOff = w << 10;

  auto stage = [&](int buf, int hp, int kt) {
    const bf16_t* src = ((hp < 2) ? pAs : pBs) + (size_t)(hp & 1) * halfStride + kt * 32;
    char* dst = ldsBase + buf * 32768 + (hp >> 1) * 16384 + (hp & 1) * 8192 + wOff;
    gload16(src, dst);
  };

  f32x4 acc[8][4] = {};

  // prologue: kt0 -> buf0, kt1 -> buf1
#pragma unroll
  for (int hp = 0; hp < 4; ++hp) stage(0, hp, 0);
#pragma unroll
  for (int hp = 0; hp < 4; ++hp) stage(1, hp, 1);
  asm volatile("s_waitcnt vmcnt(4)" ::: "memory");  // kt0 complete
  __builtin_amdgcn_s_barrier();
  __builtin_amdgcn_sched_barrier(0);

  for (int g = 0; g < G; ++g) {
    const int cb = g % 3;
    const int sb = (g + 2) % 3;
    const bool doStage = (g + 2) < G;
    char* lA = ldsBase + cb * 32768 + wm * 8192;
    char* lB = ldsBase + cb * 32768 + 16384 + (wn >> 1) * 8192;
    bf16x8 af[8], bfv[4];
#pragma unroll
    for (int i = 0; i < 8; ++i) af[i] = *(const bf16x8*)(lA + aoff[i]);
#pragma unroll
    for (int j2 = 0; j2 < 4; ++j2) bfv[j2] = *(const bf16x8*)(lB + boff[j2]);
    if (doStage) {
#pragma unroll
      for (int hp = 0; hp < 4; ++hp) stage(sb, hp, g + 2);
    }
    asm volatile("s_waitcnt lgkmcnt(0)" ::: "memory");   // own frag reads landed
    if (doStage) asm volatile("s_waitcnt vmcnt(4)" ::: "memory");  // kt g+1 landed
    else         asm volatile("s_waitcnt vmcnt(0)" ::: "memory");  // tail: drain all
    __builtin_amdgcn_sched_barrier(0);
    __builtin_amdgcn_s_barrier();   // all waves: cb reads done + kt g+1 staged
    __builtin_amdgcn_sched_barrier(0);
    __builtin_amdgcn_s_setprio(1);
#pragma unroll
    for (int i = 0; i < 8; ++i)
#pragma unroll
      for (int j2 = 0; j2 < 4; ++j2)
        acc[i][j2] = __builtin_amdgcn_mfma_f32_16x16x32_bf16(af[i], bfv[j2], acc[i][j2], 0, 0, 0);
    __builtin_amdgcn_s_setprio(0);
    __builtin_amdgcn_sched_barrier(0);
  }

  float* out = partial + (size_t)zc * MPAD * REP_;
  const int crow = (lane >> 4) * 4;
#pragma unroll
  for (int n = 0; n < 4; ++n) {
    const int col = col0 + wn * 64 + n * 16 + lr;
#pragma unroll
    for (int m = 0; m < 8; ++m) {
      const int rowb = row0 + wm * 128 + m * 16 + crow;
#pragma unroll
      for (int j2 = 0; j2 < 4; ++j2)
        out[(size_t)(rowb + j2) * REP_ + col] = acc[m][n][j2];
    }
  }
}

// ---------------- FC2/FC3: 128x128-tile 2-phase GEMM, split-K ----------------
__global__ __launch_bounds__(256) void gemm_kernel(const bf16_t* __restrict__ A,
                                                   const bf16_t* __restrict__ Bt,
                                                   float* __restrict__ partial,
                                                   int K, int ldc, int kLen) {
  __shared__ __align__(16) bf16_t As[128 * 32];
  __shared__ __align__(16) bf16_t Bs[128 * 32];
  const int t = threadIdx.x;
  const int lane = t & 63;
  const int wid = t >> 6;
  const int row0 = blockIdx.x * 128;
  const int col0 = blockIdx.y * 128;
  const int kOff = blockIdx.z * kLen;

  f32x4 acc[4][4] = {};

  const int rA = t >> 2;
  const int sA = t & 3;
  const bf16_t* aSrc1 = A + (size_t)(row0 + rA) * K + sA * 8 + kOff;
  const bf16_t* aSrc2 = A + (size_t)(row0 + rA + 64) * K + sA * 8 + kOff;
  const bf16_t* bSrc1 = Bt + (size_t)(col0 + rA) * K + sA * 8 + kOff;
  const bf16_t* bSrc2 = Bt + (size_t)(col0 + rA + 64) * K + sA * 8 + kOff;
  char* AsB = (char*)&As[0];
  char* BsB = (char*)&Bs[0];
  const int ldsOff1 = (wid * 64) * 16;
  const int ldsOff2 = (wid * 64 + 256) * 16;

  const int wm = wid >> 1;
  const int wn = wid & 1;
  const int lr = lane & 15;
  const int lk16 = (lane >> 4) * 16;
  int aOff[4], bOff[4];
#pragma unroll
  for (int m = 0; m < 4; ++m) aOff[m] = (wm * 64 + m * 16 + lr) * 64 + lk16;
#pragma unroll
  for (int n = 0; n < 4; ++n) bOff[n] = (wn * 64 + n * 16 + lr) * 64 + lk16;

  for (int k0 = 0; k0 < kLen; k0 += 32) {
    gload16(aSrc1 + k0, AsB + ldsOff1);
    gload16(aSrc2 + k0, AsB + ldsOff2);
    gload16(bSrc1 + k0, BsB + ldsOff1);
    gload16(bSrc2 + k0, BsB + ldsOff2);
    __syncthreads();
    bf16x8 af[4], bfv[4];
#pragma unroll
    for (int m = 0; m < 4; ++m) af[m] = *(const bf16x8*)(AsB + aOff[m]);
#pragma unroll
    for (int n = 0; n < 4; ++n) bfv[n] = *(const bf16x8*)(BsB + bOff[n]);
#pragma unroll
    for (int m = 0; m < 4; ++m)
#pragma unroll
      for (int n = 0; n < 4; ++n)
        acc[m][n] = __builtin_amdgcn_mfma_f32_16x16x32_bf16(af[m], bfv[n], acc[m][n], 0, 0, 0);
    __syncthreads();
  }

  float* out = partial + (size_t)blockIdx.z * MPAD * ldc;
  const int crow = (lane >> 4) * 4;
  const int ccol = lane & 15;
#pragma unroll
  for (int n = 0; n < 4; ++n) {
    const int col = col0 + wn * 64 + n * 16 + ccol;
#pragma unroll
    for (int m = 0; m < 4; ++m) {
      const int rowb = row0 + wm * 64 + m * 16 + crow;
#pragma unroll
      for (int j = 0; j < 4; ++j) {
        out[(size_t)(rowb + j) * ldc + col] = acc[m][n][j];
      }
    }
  }
}

// ---------------- split-K reduce: out = act(sum_kc partial[kc] + bias) ----------------
__global__ __launch_bounds__(256) void reduce_kernel(const float* __restrict__ partial,
                                                     const float* __restrict__ bias,
                                                     void* __restrict__ out,
                                                     int ldc, int KC, int mode) {
  const size_t idx4 = ((size_t)blockIdx.x * 256 + threadIdx.x) * 4;
  f32x4 s = *(const f32x4*)(partial + idx4);
  const size_t stride = (size_t)MPAD * ldc;
  for (int c = 1; c < KC; ++c) s += *(const f32x4*)(partial + c * stride + idx4);
  const int col = (int)(idx4 & (size_t)(ldc - 1));
  const f32x4 bv = *(const f32x4*)(bias + col);
  s += bv;
  if (mode) {
    bf16x4 o;
#pragma unroll
    for (int j = 0; j < 4; ++j) o[j] = (bf16_t)fmaxf(s[j], 0.0f);
    *(bf16x4*)((bf16_t*)out + idx4) = o;
  } else {
    *(f32x4*)((float*)out + idx4) = s;
  }
}

// ---------------- row softmax stats: one wave per row ----------------
__global__ __launch_bounds__(256) void rowsm_kernel(const float* __restrict__ ho,
                                                    float* __restrict__ mxv,
                                                    float* __restrict__ invv) {
  const int row = blockIdx.x * 4 + (threadIdx.x >> 6);
  const int lane = threadIdx.x & 63;
  if (row >= M_) return;
  const float* r = ho + (size_t)row * HOUT;
  float v1 = (lane < NCLS) ? r[lane] : -3.0e38f;
  float v2 = (lane + 64 < NCLS) ? r[lane + 64] : -3.0e38f;
  float mx = fmaxf(v1, v2);
#pragma unroll
  for (int off = 32; off; off >>= 1) mx = fmaxf(mx, __shfl_xor(mx, off));
  float s = ((lane < NCLS) ? expf(v1 - mx) : 0.0f) + ((lane + 64 < NCLS) ? expf(v2 - mx) : 0.0f);
#pragma unroll
  for (int off = 32; off; off >>= 1) s += __shfl_xor(s, off);
  if (lane == 0) { mxv[row] = mx; invv[row] = 1.0f / s; }
}

// ---------------- decode + NMS prep: one thread per (roi, class) ----------------
__global__ __launch_bounds__(256) void decode_kernel(const float* __restrict__ ho,
                                                     const float* __restrict__ mxv,
                                                     const float* __restrict__ invv,
                                                     const float* __restrict__ props,
                                                     float* __restrict__ boxes,
                                                     float* __restrict__ scores,
                                                     float* __restrict__ swork,
                                                     float* __restrict__ boff,
                                                     float* __restrict__ area) {
  const int idx = blockIdx.x * 256 + threadIdx.x;
  if (idx >= M_ * 90) return;
  const int n = idx / 90;
  const int k = idx - n * 90 + 1;
  const float* row = ho + (size_t)n * HOUT;
  const float sc = expf(row[k] - mxv[n]) * invv[n];
  const float* p = props + n * 4;
  const float px1 = p[0], py1 = p[1], px2 = p[2], py2 = p[3];
  const float pw = px2 - px1, ph = py2 - py1;
  const float pcx = px1 + 0.5f * pw, pcy = py1 + 0.5f * ph;
  const float* d = row + NCLS + 4 * k;
  const float dx = d[0] * 0.1f;
  const float dy = d[1] * 0.1f;
  const float dw = fminf(d[2] * 0.2f, BBOX_CLIPF);
  const float dh = fminf(d[3] * 0.2f, BBOX_CLIPF);
  const float cx = dx * pw + pcx, cy = dy * ph + pcy;
  const float w = pw * expf(dw), h = ph * expf(dh);
  const float bx1 = fminf(fmaxf(cx - 0.5f * w, 0.0f), IMGF);
  const float by1 = fminf(fmaxf(cy - 0.5f * h, 0.0f), IMGF);
  const float bx2 = fminf(fmaxf(cx + 0.5f * w, 0.0f), IMGF);
  const float by2 = fminf(fmaxf(cy + 0.5f * h, 0.0f), IMGF);
  const int j = idx;
  boxes[4 * j + 0] = bx1; boxes[4 * j + 1] = by1;
  boxes[4 * j + 2] = bx2; boxes[4 * j + 3] = by2;
  scores[j] = sc;
  const float wv = bx2 - bx1, hv = by2 - by1;
  swork[j] = ((sc > 0.05f) && (wv >= 1.0f) && (hv >= 1.0f)) ? sc : NEGV;
  const float off = (float)k * (IMGF + 2.0f);
  const float ox1 = bx1 + off, oy1 = by1 + off, ox2 = bx2 + off, oy2 = by2 + off;
  boff[4 * j + 0] = ox1; boff[4 * j + 1] = oy1;
  boff[4 * j + 2] = ox2; boff[4 * j + 3] = oy2;
  area[j] = (ox2 - ox1) * (oy2 - oy1);
}

// ---------------- NMS: replicates jax.lax.scan semantics exactly ----------------
__global__ __launch_bounds__(1024) void nms_kernel(const float* __restrict__ boxes,
                                                   const float* __restrict__ scores,
                                                   float* __restrict__ swork,
                                                   const float* __restrict__ boff,
                                                   const float* __restrict__ area,
                                                   float* __restrict__ dout) {
  const int b = blockIdx.x;
  const int t = threadIdx.x;
  const float* Bx = boxes + (size_t)b * NMSM * 4;
  const float* Sc = scores + (size_t)b * NMSM;
  float* Sw = swork + (size_t)b * NMSM;
  const float* Bo = boff + (size_t)b * NMSM * 4;
  const float* Ar = area + (size_t)b * NMSM;
  float* dets = dout + b * (DET_ * 5);
  float* labels = dout + B_ * DET_ * 5 + b * DET_;
  __shared__ float s_val[1024];
  __shared__ int s_idx[1024];
  __shared__ float s_box[4];
  __shared__ float s_area;
  __shared__ int s_ok;
  for (int it = 0; it < DET_; ++it) {
    float bv = -3.0e38f;
    int bi = 0;
    for (int j = t; j < NMSM; j += 1024) {
      float v = Sw[j];
      if (v > bv) { bv = v; bi = j; }
    }
    s_val[t] = bv;
    s_idx[t] = bi;
    __syncthreads();
    for (int off = 512; off > 0; off >>= 1) {
      if (t < off) {
        float v2 = s_val[t + off]; int i2 = s_idx[t + off];
        if (v2 > s_val[t] || (v2 == s_val[t] && i2 < s_idx[t])) { s_val[t] = v2; s_idx[t] = i2; }
      }
      __syncthreads();
    }
    if (t == 0) {
      int i = s_idx[0];
      int ok = (s_val[0] > NEGV * 0.5f) ? 1 : 0;
      s_ok = ok;
      if (ok) {
        dets[it * 5 + 0] = Bx[i * 4 + 0];
        dets[it * 5 + 1] = Bx[i * 4 + 1];
        dets[it * 5 + 2] = Bx[i * 4 + 2];
        dets[it * 5 + 3] = Bx[i * 4 + 3];
        dets[it * 5 + 4] = Sc[i];
        labels[it] = (float)(i % 90 + 1);
        s_box[0] = Bo[i * 4 + 0]; s_box[1] = Bo[i * 4 + 1];
        s_box[2] = Bo[i * 4 + 2]; s_box[3] = Bo[i * 4 + 3];
        s_area = Ar[i];
        Sw[i] = NEGV;
      }
    }
    __syncthreads();
    if (!s_ok) {
      for (int tt = it + t; tt < DET_; tt += 1024) {
        dets[tt * 5 + 0] = 0.0f; dets[tt * 5 + 1] = 0.0f; dets[tt * 5 + 2] = 0.0f;
        dets[tt * 5 + 3] = 0.0f; dets[tt * 5 + 4] = 0.0f;
        labels[tt] = -1.0f;
      }
      return;
    }
    const float bx1 = s_box[0], by1 = s_box[1], bx2 = s_box[2], by2 = s_box[3], ai = s_area;
    for (int j = t; j < NMSM; j += 1024) {
      float v = Sw[j];
      if (v <= NEGV * 0.5f) continue;
      float ix1 = fmaxf(bx1, Bo[j * 4 + 0]);
      float iy1 = fmaxf(by1, Bo[j * 4 + 1]);
      float ix2 = fminf(bx2, Bo[j * 4 + 2]);
      float iy2 = fminf(by2, Bo[j * 4 + 3]);
      float inter = fmaxf(ix2 - ix1, 0.0f) * fmaxf(iy2 - iy1, 0.0f);
      float iou = inter / (ai + Ar[j] - inter + 1e-9f);
      if (iou > 0.5f) Sw[j] = NEGV;
    }
    __syncthreads();
  }
}

// ---------------- launch ----------------
extern "C" void kernel_launch(void* const* d_in, const int* in_sizes, int n_in,
                              void* d_out, int out_size, void* d_ws, size_t ws_size,
                              hipStream_t stream) {
  const float* features  = (const float*)d_in[0];
  const float* proposals = (const float*)d_in[1];
  const float* w1   = (const float*)d_in[2];
  const float* b1   = (const float*)d_in[3];
  const float* w2   = (const float*)d_in[4];
  const float* b2   = (const float*)d_in[5];
  const float* wcls = (const float*)d_in[6];
  const float* bcls = (const float*)d_in[7];
  const float* wbb  = (const float*)d_in[8];
  const float* bbb  = (const float*)d_in[9];
  (void)in_sizes; (void)n_in; (void)out_size;

  char* p = (char*)d_ws;
  auto alloc = [&](size_t bytes) {
    char* r = p;
    p += (bytes + 255) & ~(size_t)255;
    return r;
  };
  bf16_t* A      = (bf16_t*)alloc((size_t)MPAD * DIN * 2);
  bf16_t* w1t    = (bf16_t*)alloc((size_t)REP_ * DIN * 2);
  bf16_t* w2t    = (bf16_t*)alloc((size_t)REP_ * REP_ * 2);
  bf16_t* wht    = (bf16_t*)alloc((size_t)HOUT * REP_ * 2);
  float*  biash  = (float*)alloc((size_t)HOUT * 4);
  bf16_t* h1     = (bf16_t*)alloc((size_t)MPAD * REP_ * 2);
  bf16_t* h2     = (bf16_t*)alloc((size_t)MPAD * REP_ * 2);
  float*  ho     = (float*)alloc((size_t)MPAD * HOUT * 4);
  float*  mxv    = (float*)alloc((size_t)M_ * 4);
  float*  invv   = (float*)alloc((size_t)M_ * 4);
  float*  boxes  = (float*)alloc((size_t)B_ * NMSM * 4 * 4);
  float*  scoresb= (float*)alloc((size_t)B_ * NMSM * 4);
  float*  sworkb = (float*)alloc((size_t)B_ * NMSM * 4);
  float*  boffb  = (float*)alloc((size_t)B_ * NMSM * 4 * 4);
  float*  areab  = (float*)alloc((size_t)B_ * NMSM * 4);

  size_t used = (size_t)(p - (char*)d_ws);
  size_t avail = (ws_size > used) ? (ws_size - used) : 0;
  float* partial = (float*)p;
  const size_t chunkB = (size_t)MPAD * REP_ * 4;   // 8 MB per chunk at ldc=1024
  int KC1 = 8;
  while (KC1 > 1 && (size_t)KC1 * chunkB > avail) KC1 >>= 1;
  int KC2 = 4;
  while (KC2 > 1 && (size_t)KC2 * chunkB > avail) KC2 >>= 1;
  int KC3 = 4;

  roi_kernel<<<dim3(C_ / CC_, (MPAD + RC_ - 1) / RC_), 256, 0, stream>>>(features, proposals, A);
  transpose_kernel<<<dim3(DIN / 32, REP_ / 32), 256, 0, stream>>>(w1, w1t, DIN, REP_);
  transpose_kernel<<<dim3(REP_ / 32, REP_ / 32), 256, 0, stream>>>(w2, w2t, REP_, REP_);
  headw_kernel<<<(HOUT * REP_) / 256, 256, 0, stream>>>(wcls, wbb, wht);
  headb_kernel<<<1, HOUT, 0, stream>>>(bcls, bbb, biash);

  // FC1: [2048 x 12544] @ [12544 x 1024] -> h1 (relu, bf16). 8-wave deep-pipelined kernel.
  gemm8_kernel<<<32 * KC1, 512, 0, stream>>>(A, w1t, partial, DIN, DIN / KC1, KC1);
  reduce_kernel<<<(MPAD * REP_ / 4) / 256, 256, 0, stream>>>(partial, b1, h1, REP_, KC1, 1);
  // FC2: [2048 x 1024] @ [1024 x 1024] -> h2 (relu, bf16)
  gemm_kernel<<<dim3(MPAD / 128, REP_ / 128, KC2), 256, 0, stream>>>(h1, w2t, partial, REP_, REP_, REP_ / KC2);
  reduce_kernel<<<(MPAD * REP_ / 4) / 256, 256, 0, stream>>>(partial, b2, h2, REP_, KC2, 1);
  // FC3 (heads): [2048 x 1024] @ [1024 x 512] -> ho (f32)
  gemm_kernel<<<dim3(MPAD / 128, HOUT / 128, KC3), 256, 0, stream>>>(h2, wht, partial, REP_, HOUT, REP_ / KC3);
  reduce_kernel<<<(MPAD * HOUT / 4) / 256, 256, 0, stream>>>(partial, biash, ho, HOUT, KC3, 0);

  rowsm_kernel<<<(M_ + 3) / 4, 256, 0, stream>>>(ho, mxv, invv);
  decode_kernel<<<(M_ * 90 + 255) / 256, 256, 0, stream>>>(ho, mxv, invv, proposals,
                                                           boxes, scoresb, sworkb, boffb, areab);
  nms_kernel<<<B_, 1024, 0, stream>>>(boxes, scoresb, sworkb, boffb, areab, (float*)d_out);
}

// Round 9
// 192.315 us; speedup vs baseline: 1.3197x; 1.0346x over previous
//
#include <hip/hip_runtime.h>
#include <stdint.h>

// ---------------- problem constants (hard-coded from reference) ----------------
#define B_    2
#define N_    1000
#define C_    256
#define H_    50
#define W_    50
#define P_    7
#define NCLS  91
#define REP_  1024
#define DIN   (C_ * P_ * P_)   // 12544
#define M_    (B_ * N_)        // 2000
#define MPAD  2048
#define HOUT  512              // padded head cols (91 cls + 364 bbox = 455 real)
#define DET_  100
#define NMSM  (N_ * 90)        // 90000 candidates per batch
#define NEGV  (-1000000000.0f)
#define SCALE_ 0.0625f
#define IMGF  800.0f
#define BBOX_CLIPF 4.135166556742356f  // log(1000/16)

#define RC_   25               // rois per roi-chunk (1000 % 25 == 0: no batch mixing)
#define CC_   4                // channels per channel-chunk

typedef __bf16 bf16_t;
typedef __attribute__((ext_vector_type(8))) __bf16 bf16x8;
typedef __attribute__((ext_vector_type(4))) __bf16 bf16x4;
typedef __attribute__((ext_vector_type(4))) float f32x4;

// async global->LDS, 16B per lane. LDS dest must be wave-uniform base (+lane*16 by HW).
__device__ __forceinline__ void gload16(const void* g, void* l) {
  auto gp = (const __attribute__((address_space(1))) uint32_t*)(uintptr_t)g;
  auto lp = (__attribute__((address_space(3))) uint32_t*)(uint32_t)(uintptr_t)l;
  __builtin_amdgcn_global_load_lds(gp, lp, 16, 0, 0);
}

// ---------------- ROI align: LDS-staged feature planes, gathers from LDS ----------------
__global__ __launch_bounds__(256) void roi_kernel(const float* __restrict__ features,
                                                  const float* __restrict__ proposals,
                                                  bf16_t* __restrict__ A) {
  const int cc0 = blockIdx.x * CC_;       // channel base (0..252)
  const int roiBase = blockIdx.y * RC_;   // roi base
  const int t = threadIdx.x;
  if (roiBase >= M_) {
    for (int idx = t; idx < RC_ * 49; idx += 256) {
      const int r = idx / 49, pp = idx - r * 49;
      const int n = roiBase + r;
      if (n < MPAD) {
        bf16_t* arow = A + (size_t)n * DIN + cc0 * 49 + pp;
#pragma unroll
        for (int c = 0; c < CC_; ++c) arow[c * 49] = (bf16_t)0.0f;
      }
    }
    return;
  }
  __shared__ __align__(16) float s_pl[CC_ * 2500];   // 40000 B
  __shared__ float s_ly[RC_ * 49];
  __shared__ float s_lx[RC_ * 49];
  __shared__ unsigned short s_off[RC_ * 49];
  const int b = (roiBase >= N_) ? 1 : 0;
  const f32x4* src = (const f32x4*)(features + (size_t)(b * C_ + cc0) * (H_ * W_));
  f32x4* dst = (f32x4*)s_pl;
  for (int i = t; i < CC_ * 2500 / 4; i += 256) dst[i] = src[i];
  for (int idx = t; idx < RC_ * 49; idx += 256) {
    const int r = idx / 49, pp = idx - r * 49;
    const int py = pp / 7, px = pp - py * 7;
    const float* p = proposals + (roiBase + r) * 4;
    float y1 = p[1] * SCALE_, y2 = p[3] * SCALE_;
    float bh = (y2 - y1) * (1.0f / 7.0f);
    float y = y1 + ((float)py + 0.5f) * bh - 0.5f;
    y = fminf(fmaxf(y, 0.0f), 49.0f);
    int y0 = (int)floorf(y);
    int dy = (y0 < 49) ? 1 : 0;
    float ly = y - (float)y0;
    float x1 = p[0] * SCALE_, x2 = p[2] * SCALE_;
    float bw = (x2 - x1) * (1.0f / 7.0f);
    float x = x1 + ((float)px + 0.5f) * bw - 0.5f;
    x = fminf(fmaxf(x, 0.0f), 49.0f);
    int x0 = (int)floorf(x);
    int dx = (x0 < 49) ? 1 : 0;
    float lx = x - (float)x0;
    s_off[idx] = (unsigned short)((y0 * W_ + x0) | (dx << 12) | (dy << 13));
    s_ly[idx] = ly;
    s_lx[idx] = lx;
  }
  __syncthreads();
  for (int idx = t; idx < RC_ * 49; idx += 256) {
    const int r = idx / 49, pp = idx - r * 49;
    const unsigned off = s_off[idx];
    const float ly = s_ly[idx], lx = s_lx[idx];
    const float hy = 1.0f - ly, hx = 1.0f - lx;
    const int o00 = off & 0xFFF;
    const int dx = (off >> 12) & 1;
    const int o10 = o00 + W_ * ((off >> 13) & 1);
    const float w00 = hy * hx, w01 = hy * lx, w10 = ly * hx, w11 = ly * lx;
    bf16_t* arow = A + (size_t)(roiBase + r) * DIN + cc0 * 49 + pp;
#pragma unroll
    for (int c = 0; c < CC_; ++c) {
      const float* pl = s_pl + c * 2500;
      float v = pl[o00] * w00 + pl[o00 + dx] * w01 + pl[o10] * w10 + pl[o10 + dx] * w11;
      arow[c * 49] = (bf16_t)v;
    }
  }
}

// ---------------- transpose+convert: in f32 [K][N] -> out bf16 [N][K] ----------------
__global__ __launch_bounds__(256) void transpose_kernel(const float* __restrict__ in,
                                                        bf16_t* __restrict__ out,
                                                        int K, int N) {
  __shared__ float tile[32][33];
  const int k0 = blockIdx.x * 32;
  const int n0 = blockIdx.y * 32;
  const int tx = threadIdx.x & 31;
  const int ty = threadIdx.x >> 5;
#pragma unroll
  for (int j = 0; j < 4; ++j) {
    int ky = ty + j * 8;
    tile[ky][tx] = in[(size_t)(k0 + ky) * N + n0 + tx];
  }
  __syncthreads();
  const int qx = threadIdx.x & 7;
  const int ny = threadIdx.x >> 3;
  bf16x4 o;
#pragma unroll
  for (int i = 0; i < 4; ++i) o[i] = (bf16_t)tile[4 * qx + i][ny];
  *(bf16x4*)(&out[(size_t)(n0 + ny) * K + k0 + 4 * qx]) = o;
}

// ---------------- build concat head weight (B^T) and bias ----------------
__global__ __launch_bounds__(256) void headw_kernel(const float* __restrict__ wcls,
                                                    const float* __restrict__ wbb,
                                                    bf16_t* __restrict__ wht) {
  int idx = blockIdx.x * 256 + threadIdx.x;
  int j = idx >> 10;
  int k = idx & 1023;
  float v = 0.0f;
  if (j < NCLS) v = wcls[(size_t)k * NCLS + j];
  else if (j < 455) v = wbb[(size_t)k * 364 + (j - NCLS)];
  wht[idx] = (bf16_t)v;
}

__global__ void headb_kernel(const float* __restrict__ bcls,
                             const float* __restrict__ bbb,
                             float* __restrict__ biash) {
  int j = threadIdx.x;
  float v = 0.0f;
  if (j < NCLS) v = bcls[j];
  else if (j < 455) v = bbb[j - NCLS];
  biash[j] = v;
}

// ---------------- FC1: 256x256-tile deep-pipelined MFMA GEMM (8-wave, split-K) ----------------
// 4 LDS buffers (128 KiB), depth-3 prefetch (stage kt g+3 FIRST, steady vmcnt(8)),
// one-shot frag reads, single barrier/K-tile, st_16x32 swizzle both-sides,
// zc = bid % KC pins each K-chunk to one XCD. Partials written as bf16.
__global__ __launch_bounds__(512, 2) void gemm8_kernel(const bf16_t* __restrict__ A,
                                                       const bf16_t* __restrict__ Bt,
                                                       bf16_t* __restrict__ partial,
                                                       int K, int kLen, int KC) {
  __shared__ __align__(16) bf16_t lds[4 * 2 * 2 * 128 * 32];  // 128 KiB
  const int t = threadIdx.x;
  const int lane = t & 63;
  const int w = t >> 6;         // 0..7
  const int wm = w >> 2;        // 0..1  (A-half / M region)
  const int wn = w & 3;         // 0..3  (64-col strip)
  const int bid = blockIdx.x;
  const int zc = bid % KC;      // K-chunk == XCD under round-robin dispatch
  const int inner = bid / KC;   // 0..31
  const int row0 = (inner >> 2) * 256;
  const int col0 = (inner & 3) * 256;
  const int kOff = zc * kLen;
  const int G = kLen >> 5;      // 32-deep K-tiles (>= 3)

  const int lr = lane & 15;
  const int kb = (lane >> 4) * 16;
  int aoff[8], boff[4];
#pragma unroll
  for (int m = 0; m < 8; ++m) {
    int r = m * 16 + lr;
    aoff[m] = (r * 64 + kb) ^ (((r >> 3) & 1) << 5);
  }
#pragma unroll
  for (int n = 0; n < 4; ++n) {
    int r = (wn & 1) * 64 + n * 16 + lr;
    boff[n] = (r * 64 + kb) ^ (((r >> 3) & 1) << 5);
  }

  const int s_row = t >> 2;
  const int s_k8 = (t & 3) ^ (((s_row >> 3) & 1) << 1);
  const bf16_t* pAs = A + (size_t)(row0 + s_row) * K + kOff + s_k8 * 8;
  const bf16_t* pBs = Bt + (size_t)(col0 + s_row) * K + kOff + s_k8 * 8;
  const size_t halfStride = (size_t)128 * K;
  char* ldsBase = (char*)&lds[0];
  const int wOff = w << 10;

  auto stage = [&](int buf, int hp, int kt) {
    const bf16_t* src = ((hp < 2) ? pAs : pBs) + (size_t)(hp & 1) * halfStride + kt * 32;
    char* dst = ldsBase + buf * 32768 + (hp >> 1) * 16384 + (hp & 1) * 8192 + wOff;
    gload16(src, dst);
  };

  f32x4 acc[8][4] = {};

  // prologue: kt0->buf0, kt1->buf1, kt2->buf2 (12 loads); wait kt0 (vmcnt 8)
#pragma unroll
  for (int hp = 0; hp < 4; ++hp) stage(0, hp, 0);
#pragma unroll
  for (int hp = 0; hp < 4; ++hp) stage(1, hp, 1);
#pragma unroll
  for (int hp = 0; hp < 4; ++hp) stage(2, hp, 2);
  asm volatile("s_waitcnt vmcnt(8)" ::: "memory");
  __builtin_amdgcn_s_barrier();
  __builtin_amdgcn_sched_barrier(0);

  for (int g = 0; g < G; ++g) {
    const int cb = g & 3;
    const int sb = (g + 3) & 3;
    const bool doStage = (g + 3) < G;
    // issue next-next-next tile FIRST: maximal latency cover
    if (doStage) {
#pragma unroll
      for (int hp = 0; hp < 4; ++hp) stage(sb, hp, g + 3);
    }
    char* lA = ldsBase + cb * 32768 + wm * 8192;
    char* lB = ldsBase + cb * 32768 + 16384 + (wn >> 1) * 8192;
    bf16x8 af[8], bfv[4];
#pragma unroll
    for (int i = 0; i < 8; ++i) af[i] = *(const bf16x8*)(lA + aoff[i]);
#pragma unroll
    for (int j2 = 0; j2 < 4; ++j2) bfv[j2] = *(const bf16x8*)(lB + boff[j2]);
    asm volatile("s_waitcnt lgkmcnt(0)" ::: "memory");   // own frag reads landed
    if (doStage)          asm volatile("s_waitcnt vmcnt(8)" ::: "memory");  // kt g+1 landed
    else if (g == G - 3)  asm volatile("s_waitcnt vmcnt(4)" ::: "memory");
    else                  asm volatile("s_waitcnt vmcnt(0)" ::: "memory");
    __builtin_amdgcn_sched_barrier(0);
    __builtin_amdgcn_s_barrier();   // all waves: cb reads done + kt g+1 staged
    __builtin_amdgcn_sched_barrier(0);
    __builtin_amdgcn_s_setprio(1);
#pragma unroll
    for (int i = 0; i < 8; ++i)
#pragma unroll
      for (int j2 = 0; j2 < 4; ++j2)
        acc[i][j2] = __builtin_amdgcn_mfma_f32_16x16x32_bf16(af[i], bfv[j2], acc[i][j2], 0, 0, 0);
    __builtin_amdgcn_s_setprio(0);
    __builtin_amdgcn_sched_barrier(0);
  }

  // epilogue: bf16 partial write (halves reduce traffic). C/D: col=lane&15, row=(lane>>4)*4+reg
  bf16_t* out = partial + (size_t)zc * MPAD * REP_;
  const int crow = (lane >> 4) * 4;
#pragma unroll
  for (int n = 0; n < 4; ++n) {
    const int col = col0 + wn * 64 + n * 16 + lr;
#pragma unroll
    for (int m = 0; m < 8; ++m) {
      const int rowb = row0 + wm * 128 + m * 16 + crow;
#pragma unroll
      for (int j2 = 0; j2 < 4; ++j2)
        out[(size_t)(rowb + j2) * REP_ + col] = (bf16_t)acc[m][n][j2];
    }
  }
}

// ---------------- FC2/FC3: 128x128-tile 2-phase GEMM, split-K ----------------
__global__ __launch_bounds__(256) void gemm_kernel(const bf16_t* __restrict__ A,
                                                   const bf16_t* __restrict__ Bt,
                                                   float* __restrict__ partial,
                                                   int K, int ldc, int kLen) {
  __shared__ __align__(16) bf16_t As[128 * 32];
  __shared__ __align__(16) bf16_t Bs[128 * 32];
  const int t = threadIdx.x;
  const int lane = t & 63;
  const int wid = t >> 6;
  const int row0 = blockIdx.x * 128;
  const int col0 = blockIdx.y * 128;
  const int kOff = blockIdx.z * kLen;

  f32x4 acc[4][4] = {};

  const int rA = t >> 2;
  const int sA = t & 3;
  const bf16_t* aSrc1 = A + (size_t)(row0 + rA) * K + sA * 8 + kOff;
  const bf16_t* aSrc2 = A + (size_t)(row0 + rA + 64) * K + sA * 8 + kOff;
  const bf16_t* bSrc1 = Bt + (size_t)(col0 + rA) * K + sA * 8 + kOff;
  const bf16_t* bSrc2 = Bt + (size_t)(col0 + rA + 64) * K + sA * 8 + kOff;
  char* AsB = (char*)&As[0];
  char* BsB = (char*)&Bs[0];
  const int ldsOff1 = (wid * 64) * 16;
  const int ldsOff2 = (wid * 64 + 256) * 16;

  const int wm = wid >> 1;
  const int wn = wid & 1;
  const int lr = lane & 15;
  const int lk16 = (lane >> 4) * 16;
  int aOff[4], bOff[4];
#pragma unroll
  for (int m = 0; m < 4; ++m) aOff[m] = (wm * 64 + m * 16 + lr) * 64 + lk16;
#pragma unroll
  for (int n = 0; n < 4; ++n) bOff[n] = (wn * 64 + n * 16 + lr) * 64 + lk16;

  for (int k0 = 0; k0 < kLen; k0 += 32) {
    gload16(aSrc1 + k0, AsB + ldsOff1);
    gload16(aSrc2 + k0, AsB + ldsOff2);
    gload16(bSrc1 + k0, BsB + ldsOff1);
    gload16(bSrc2 + k0, BsB + ldsOff2);
    __syncthreads();
    bf16x8 af[4], bfv[4];
#pragma unroll
    for (int m = 0; m < 4; ++m) af[m] = *(const bf16x8*)(AsB + aOff[m]);
#pragma unroll
    for (int n = 0; n < 4; ++n) bfv[n] = *(const bf16x8*)(BsB + bOff[n]);
#pragma unroll
    for (int m = 0; m < 4; ++m)
#pragma unroll
      for (int n = 0; n < 4; ++n)
        acc[m][n] = __builtin_amdgcn_mfma_f32_16x16x32_bf16(af[m], bfv[n], acc[m][n], 0, 0, 0);
    __syncthreads();
  }

  float* out = partial + (size_t)blockIdx.z * MPAD * ldc;
  const int crow = (lane >> 4) * 4;
  const int ccol = lane & 15;
#pragma unroll
  for (int n = 0; n < 4; ++n) {
    const int col = col0 + wn * 64 + n * 16 + ccol;
#pragma unroll
    for (int m = 0; m < 4; ++m) {
      const int rowb = row0 + wm * 64 + m * 16 + crow;
#pragma unroll
      for (int j = 0; j < 4; ++j) {
        out[(size_t)(rowb + j) * ldc + col] = acc[m][n][j];
      }
    }
  }
}

// ---------------- FC1 reduce: bf16 partials -> relu -> bf16 out (8 elems/thread) ----------------
__global__ __launch_bounds__(256) void reduceH_kernel(const bf16_t* __restrict__ partial,
                                                      const float* __restrict__ bias,
                                                      bf16_t* __restrict__ out,
                                                      int KC) {
  const size_t idx8 = ((size_t)blockIdx.x * 256 + threadIdx.x) * 8;  // over MPAD*REP_
  const size_t stride = (size_t)MPAD * REP_;
  float s[8] = {};
  for (int c = 0; c < KC; ++c) {
    const bf16x8 v = *(const bf16x8*)(partial + c * stride + idx8);
#pragma unroll
    for (int j = 0; j < 8; ++j) s[j] += (float)v[j];
  }
  const int col = (int)(idx8 & (size_t)(REP_ - 1));
  const f32x4 b0 = *(const f32x4*)(bias + col);
  const f32x4 b1 = *(const f32x4*)(bias + col + 4);
  bf16x8 o;
#pragma unroll
  for (int j = 0; j < 4; ++j) o[j] = (bf16_t)fmaxf(s[j] + b0[j], 0.0f);
#pragma unroll
  for (int j = 0; j < 4; ++j) o[4 + j] = (bf16_t)fmaxf(s[4 + j] + b1[j], 0.0f);
  *(bf16x8*)(out + idx8) = o;
}

// ---------------- split-K reduce (f32 partials) ----------------
__global__ __launch_bounds__(256) void reduce_kernel(const float* __restrict__ partial,
                                                     const float* __restrict__ bias,
                                                     void* __restrict__ out,
                                                     int ldc, int KC, int mode) {
  const size_t idx4 = ((size_t)blockIdx.x * 256 + threadIdx.x) * 4;
  f32x4 s = *(const f32x4*)(partial + idx4);
  const size_t stride = (size_t)MPAD * ldc;
  for (int c = 1; c < KC; ++c) s += *(const f32x4*)(partial + c * stride + idx4);
  const int col = (int)(idx4 & (size_t)(ldc - 1));
  const f32x4 bv = *(const f32x4*)(bias + col);
  s += bv;
  if (mode) {
    bf16x4 o;
#pragma unroll
    for (int j = 0; j < 4; ++j) o[j] = (bf16_t)fmaxf(s[j], 0.0f);
    *(bf16x4*)((bf16_t*)out + idx4) = o;
  } else {
    *(f32x4*)((float*)out + idx4) = s;
  }
}

// ---------------- row softmax stats: one wave per row ----------------
__global__ __launch_bounds__(256) void rowsm_kernel(const float* __restrict__ ho,
                                                    float* __restrict__ mxv,
                                                    float* __restrict__ invv) {
  const int row = blockIdx.x * 4 + (threadIdx.x >> 6);
  const int lane = threadIdx.x & 63;
  if (row >= M_) return;
  const float* r = ho + (size_t)row * HOUT;
  float v1 = (lane < NCLS) ? r[lane] : -3.0e38f;
  float v2 = (lane + 64 < NCLS) ? r[lane + 64] : -3.0e38f;
  float mx = fmaxf(v1, v2);
#pragma unroll
  for (int off = 32; off; off >>= 1) mx = fmaxf(mx, __shfl_xor(mx, off));
  float s = ((lane < NCLS) ? expf(v1 - mx) : 0.0f) + ((lane + 64 < NCLS) ? expf(v2 - mx) : 0.0f);
#pragma unroll
  for (int off = 32; off; off >>= 1) s += __shfl_xor(s, off);
  if (lane == 0) { mxv[row] = mx; invv[row] = 1.0f / s; }
}

// ---------------- decode + NMS prep: one thread per (roi, class) ----------------
__global__ __launch_bounds__(256) void decode_kernel(const float* __restrict__ ho,
                                                     const float* __restrict__ mxv,
                                                     const float* __restrict__ invv,
                                                     const float* __restrict__ props,
                                                     float* __restrict__ boxes,
                                                     float* __restrict__ scores,
                                                     float* __restrict__ swork,
                                                     float* __restrict__ boff,
                                                     float* __restrict__ area) {
  const int idx = blockIdx.x * 256 + threadIdx.x;
  if (idx >= M_ * 90) return;
  const int n = idx / 90;
  const int k = idx - n * 90 + 1;
  const float* row = ho + (size_t)n * HOUT;
  const float sc = expf(row[k] - mxv[n]) * invv[n];
  const float* p = props + n * 4;
  const float px1 = p[0], py1 = p[1], px2 = p[2], py2 = p[3];
  const float pw = px2 - px1, ph = py2 - py1;
  const float pcx = px1 + 0.5f * pw, pcy = py1 + 0.5f * ph;
  const float* d = row + NCLS + 4 * k;
  const float dx = d[0] * 0.1f;
  const float dy = d[1] * 0.1f;
  const float dw = fminf(d[2] * 0.2f, BBOX_CLIPF);
  const float dh = fminf(d[3] * 0.2f, BBOX_CLIPF);
  const float cx = dx * pw + pcx, cy = dy * ph + pcy;
  const float w = pw * expf(dw), h = ph * expf(dh);
  const float bx1 = fminf(fmaxf(cx - 0.5f * w, 0.0f), IMGF);
  const float by1 = fminf(fmaxf(cy - 0.5f * h, 0.0f), IMGF);
  const float bx2 = fminf(fmaxf(cx + 0.5f * w, 0.0f), IMGF);
  const float by2 = fminf(fmaxf(cy + 0.5f * h, 0.0f), IMGF);
  const int j = idx;
  boxes[4 * j + 0] = bx1; boxes[4 * j + 1] = by1;
  boxes[4 * j + 2] = bx2; boxes[4 * j + 3] = by2;
  scores[j] = sc;
  const float wv = bx2 - bx1, hv = by2 - by1;
  swork[j] = ((sc > 0.05f) && (wv >= 1.0f) && (hv >= 1.0f)) ? sc : NEGV;
  const float off = (float)k * (IMGF + 2.0f);
  const float ox1 = bx1 + off, oy1 = by1 + off, ox2 = bx2 + off, oy2 = by2 + off;
  boff[4 * j + 0] = ox1; boff[4 * j + 1] = oy1;
  boff[4 * j + 2] = ox2; boff[4 * j + 3] = oy2;
  area[j] = (ox2 - ox1) * (oy2 - oy1);
}

// ---------------- NMS: replicates jax.lax.scan semantics exactly ----------------
__global__ __launch_bounds__(1024) void nms_kernel(const float* __restrict__ boxes,
                                                   const float* __restrict__ scores,
                                                   float* __restrict__ swork,
                                                   const float* __restrict__ boff,
                                                   const float* __restrict__ area,
                                                   float* __restrict__ dout) {
  const int b = blockIdx.x;
  const int t = threadIdx.x;
  const float* Bx = boxes + (size_t)b * NMSM * 4;
  const float* Sc = scores + (size_t)b * NMSM;
  float* Sw = swork + (size_t)b * NMSM;
  const float* Bo = boff + (size_t)b * NMSM * 4;
  const float* Ar = area + (size_t)b * NMSM;
  float* dets = dout + b * (DET_ * 5);
  float* labels = dout + B_ * DET_ * 5 + b * DET_;
  __shared__ float s_val[1024];
  __shared__ int s_idx[1024];
  __shared__ float s_box[4];
  __shared__ float s_area;
  __shared__ int s_ok;
  for (int it = 0; it < DET_; ++it) {
    float bv = -3.0e38f;
    int bi = 0;
    for (int j = t; j < NMSM; j += 1024) {
      float v = Sw[j];
      if (v > bv) { bv = v; bi = j; }
    }
    s_val[t] = bv;
    s_idx[t] = bi;
    __syncthreads();
    for (int off = 512; off > 0; off >>= 1) {
      if (t < off) {
        float v2 = s_val[t + off]; int i2 = s_idx[t + off];
        if (v2 > s_val[t] || (v2 == s_val[t] && i2 < s_idx[t])) { s_val[t] = v2; s_idx[t] = i2; }
      }
      __syncthreads();
    }
    if (t == 0) {
      int i = s_idx[0];
      int ok = (s_val[0] > NEGV * 0.5f) ? 1 : 0;
      s_ok = ok;
      if (ok) {
        dets[it * 5 + 0] = Bx[i * 4 + 0];
        dets[it * 5 + 1] = Bx[i * 4 + 1];
        dets[it * 5 + 2] = Bx[i * 4 + 2];
        dets[it * 5 + 3] = Bx[i * 4 + 3];
        dets[it * 5 + 4] = Sc[i];
        labels[it] = (float)(i % 90 + 1);
        s_box[0] = Bo[i * 4 + 0]; s_box[1] = Bo[i * 4 + 1];
        s_box[2] = Bo[i * 4 + 2]; s_box[3] = Bo[i * 4 + 3];
        s_area = Ar[i];
        Sw[i] = NEGV;
      }
    }
    __syncthreads();
    if (!s_ok) {
      for (int tt = it + t; tt < DET_; tt += 1024) {
        dets[tt * 5 + 0] = 0.0f; dets[tt * 5 + 1] = 0.0f; dets[tt * 5 + 2] = 0.0f;
        dets[tt * 5 + 3] = 0.0f; dets[tt * 5 + 4] = 0.0f;
        labels[tt] = -1.0f;
      }
      return;
    }
    const float bx1 = s_box[0], by1 = s_box[1], bx2 = s_box[2], by2 = s_box[3], ai = s_area;
    for (int j = t; j < NMSM; j += 1024) {
      float v = Sw[j];
      if (v <= NEGV * 0.5f) continue;
      float ix1 = fmaxf(bx1, Bo[j * 4 + 0]);
      float iy1 = fmaxf(by1, Bo[j * 4 + 1]);
      float ix2 = fminf(bx2, Bo[j * 4 + 2]);
      float iy2 = fminf(by2, Bo[j * 4 + 3]);
      float inter = fmaxf(ix2 - ix1, 0.0f) * fmaxf(iy2 - iy1, 0.0f);
      float iou = inter / (ai + Ar[j] - inter + 1e-9f);
      if (iou > 0.5f) Sw[j] = NEGV;
    }
    __syncthreads();
  }
}

// ---------------- launch ----------------
extern "C" void kernel_launch(void* const* d_in, const int* in_sizes, int n_in,
                              void* d_out, int out_size, void* d_ws, size_t ws_size,
                              hipStream_t stream) {
  const float* features  = (const float*)d_in[0];
  const float* proposals = (const float*)d_in[1];
  const float* w1   = (const float*)d_in[2];
  const float* b1   = (const float*)d_in[3];
  const float* w2   = (const float*)d_in[4];
  const float* b2   = (const float*)d_in[5];
  const float* wcls = (const float*)d_in[6];
  const float* bcls = (const float*)d_in[7];
  const float* wbb  = (const float*)d_in[8];
  const float* bbb  = (const float*)d_in[9];
  (void)in_sizes; (void)n_in; (void)out_size;

  char* p = (char*)d_ws;
  auto alloc = [&](size_t bytes) {
    char* r = p;
    p += (bytes + 255) & ~(size_t)255;
    return r;
  };
  bf16_t* A      = (bf16_t*)alloc((size_t)MPAD * DIN * 2);
  bf16_t* w1t    = (bf16_t*)alloc((size_t)REP_ * DIN * 2);
  bf16_t* w2t    = (bf16_t*)alloc((size_t)REP_ * REP_ * 2);
  bf16_t* wht    = (bf16_t*)alloc((size_t)HOUT * REP_ * 2);
  float*  biash  = (float*)alloc((size_t)HOUT * 4);
  bf16_t* h1     = (bf16_t*)alloc((size_t)MPAD * REP_ * 2);
  bf16_t* h2     = (bf16_t*)alloc((size_t)MPAD * REP_ * 2);
  float*  ho     = (float*)alloc((size_t)MPAD * HOUT * 4);
  float*  mxv    = (float*)alloc((size_t)M_ * 4);
  float*  invv   = (float*)alloc((size_t)M_ * 4);
  float*  boxes  = (float*)alloc((size_t)B_ * NMSM * 4 * 4);
  float*  scoresb= (float*)alloc((size_t)B_ * NMSM * 4);
  float*  sworkb = (float*)alloc((size_t)B_ * NMSM * 4);
  float*  boffb  = (float*)alloc((size_t)B_ * NMSM * 4 * 4);
  float*  areab  = (float*)alloc((size_t)B_ * NMSM * 4);

  size_t used = (size_t)(p - (char*)d_ws);
  size_t avail = (ws_size > used) ? (ws_size - used) : 0;
  bf16_t* partialH = (bf16_t*)p;   // bf16 partials (FC1)
  float*  partialF = (float*)p;    // f32 partials (FC2/FC3, stream-ordered reuse)
  const size_t chunkH = (size_t)MPAD * REP_ * 2;   // 4 MB
  const size_t chunkF = (size_t)MPAD * REP_ * 4;   // 8 MB
  int KC1 = 8;
  while (KC1 > 1 && (size_t)KC1 * chunkH > avail) KC1 >>= 1;
  int KC2 = 4;
  while (KC2 > 1 && (size_t)KC2 * chunkF > avail) KC2 >>= 1;
  int KC3 = 4;

  roi_kernel<<<dim3(C_ / CC_, (MPAD + RC_ - 1) / RC_), 256, 0, stream>>>(features, proposals, A);
  transpose_kernel<<<dim3(DIN / 32, REP_ / 32), 256, 0, stream>>>(w1, w1t, DIN, REP_);
  transpose_kernel<<<dim3(REP_ / 32, REP_ / 32), 256, 0, stream>>>(w2, w2t, REP_, REP_);
  headw_kernel<<<(HOUT * REP_) / 256, 256, 0, stream>>>(wcls, wbb, wht);
  headb_kernel<<<1, HOUT, 0, stream>>>(bcls, bbb, biash);

  // FC1: [2048 x 12544] @ [12544 x 1024] -> h1 (relu, bf16). 8-wave depth-3 pipeline.
  gemm8_kernel<<<32 * KC1, 512, 0, stream>>>(A, w1t, partialH, DIN, DIN / KC1, KC1);
  reduceH_kernel<<<(MPAD * REP_ / 8) / 256, 256, 0, stream>>>(partialH, b1, h1, KC1);
  // FC2: [2048 x 1024] @ [1024 x 1024] -> h2 (relu, bf16)
  gemm_kernel<<<dim3(MPAD / 128, REP_ / 128, KC2), 256, 0, stream>>>(h1, w2t, partialF, REP_, REP_, REP_ / KC2);
  reduce_kernel<<<(MPAD * REP_ / 4) / 256, 256, 0, stream>>>(partialF, b2, h2, REP_, KC2, 1);
  // FC3 (heads): [2048 x 1024] @ [1024 x 512] -> ho (f32)
  gemm_kernel<<<dim3(MPAD / 128, HOUT / 128, KC3), 256, 0, stream>>>(h2, wht, partialF, REP_, HOUT, REP_ / KC3);
  reduce_kernel<<<(MPAD * HOUT / 4) / 256, 256, 0, stream>>>(partialF, biash, ho, HOUT, KC3, 0);

  rowsm_kernel<<<(M_ + 3) / 4, 256, 0, stream>>>(ho, mxv, invv);
  decode_kernel<<<(M_ * 90 + 255) / 256, 256, 0, stream>>>(ho, mxv, invv, proposals,
                                                           boxes, scoresb, sworkb, boffb, areab);
  nms_kernel<<<B_, 1024, 0, stream>>>(boxes, scoresb, sworkb, boffb, areab, (float*)d_out);
}